// Round 2
// baseline (2802.593 us; speedup 1.0000x reference)
//
#include <hip/hip_runtime.h>
#include <hip/hip_bf16.h>
#include <cstdint>
#include <cstddef>

// Problem constants
#define B_SZ   256
#define T_SZ   2049
#define D_SZ   64
#define H_SZ   64
#define MLP_SZ 128
#define NI_SZ  128
#define SEG    16          // (T-1)/NI
#define KDIM   2080        // L = D + D(D-1)/2
#define KP     2112        // padded K = 33*64 (BK=64 tiles)
#define OUT_SZ 10

// GEMM shapes
#define NC     32                  // intervals per chunk
#define NCHUNK (NI_SZ / NC)        // 4
#define MROWS  (NC * B_SZ)         // 8192 rows per chunk GEMM
#define NB     8448                // padded B rows = 33*256
#define GSTR   8256                // stored C cols (8192 G + 64 b2) = G row stride
#define NT     (KP / 64)           // 33 K-tiles

typedef _Float16 f16x8 __attribute__((ext_vector_type(8)));
typedef float    f32x4 __attribute__((ext_vector_type(4)));
typedef float    f32x16 __attribute__((ext_vector_type(16)));

__device__ __forceinline__ float rlane(float v, int l) {
    return __uint_as_float(__builtin_amdgcn_readlane(__float_as_uint(v), l));
}

// ---------------------------------------------------------------------------
// Build Bmat (fp16, [NB x KP] row-major), PERMUTED columns-of-G order:
//   row r' = d*128 + m  (d<64, m<128) holds W2[m][d*L + l]
//   rows 8192..8255: b2 row d  |  rows 8256..8447: zeros  |  k pad 2080..2111: 0
// ---------------------------------------------------------------------------
__global__ __launch_bounds__(256) void build_B(const float* __restrict__ W2,
                                               const float* __restrict__ b2,
                                               _Float16* __restrict__ Bm) {
    const int r = blockIdx.x, t = threadIdx.x;
    const float* src = nullptr;
    if (r < 8192) {
        const int d = r >> 7, m = r & 127;
        src = W2 + (size_t)m * (64 * KDIM) + (size_t)d * KDIM;
    } else if (r < 8256) {
        src = b2 + (size_t)(r - 8192) * KDIM;
    }
    _Float16* dst = Bm + (size_t)r * KP;
    for (int l = t; l < KP; l += 256)
        dst[l] = (src && l < KDIM) ? (_Float16)src[l] : (_Float16)0.0f;
}

// ---------------------------------------------------------------------------
// h0 = X[:,0,:] @ W_in + b_in          <<<256, 64>>>
// ---------------------------------------------------------------------------
__global__ void h0_kernel(const float* __restrict__ X, const float* __restrict__ W_in,
                          const float* __restrict__ b_in, float* __restrict__ h_state) {
    const int b = blockIdx.x, t = threadIdx.x;
    __shared__ float x0[D_SZ];
    if (t < D_SZ) x0[t] = X[(size_t)b * T_SZ * D_SZ + t];
    __syncthreads();
    float acc = b_in[t];
    for (int k = 0; k < D_SZ; ++k) acc += x0[k] * W_in[k * H_SZ + t];
    h_state[b * H_SZ + t] = acc;
}

// ---------------------------------------------------------------------------
// Depth-2 log-signature, tile-structured (4x4 register tiles, Lyndon order).
// grid (256, NC), 256 threads. Rows written with stride KP, pad zeroed.
// ---------------------------------------------------------------------------
__global__ __launch_bounds__(256) void logsig_kernel(const float* __restrict__ X,
                                                     _Float16* __restrict__ LS,
                                                     int n0) {
    const int b = blockIdx.x, sl = blockIdx.y, t = threadIdx.x;
    const int n = n0 + sl;
    __shared__ float seg[SEG + 1][D_SZ];
    __shared__ float cum[SEG][D_SZ];
    __shared__ float dlt[SEG][D_SZ];
    __shared__ float Mm[D_SZ][D_SZ + 1];   // +1 pad: transpose reads conflict-free

    const float* Xp = X + ((size_t)b * T_SZ + (size_t)n * SEG) * D_SZ;
    for (int i = t; i < (SEG + 1) * D_SZ / 4; i += 256)
        ((float4*)&seg[0][0])[i] = ((const float4*)Xp)[i];
    __syncthreads();
    for (int i = t; i < SEG * D_SZ; i += 256) {
        const int k = i >> 6, d = i & 63;
        cum[k][d] = seg[k][d] - seg[0][d];
        dlt[k][d] = seg[k + 1][d] - seg[k][d];
    }
    __syncthreads();

    const int ti = t >> 4, tj = t & 15;
    const int i0 = ti * 4, j0 = tj * 4;
    float m4[4][4] = {};
#pragma unroll
    for (int k = 0; k < SEG; ++k) {
        const float4 ci = *(const float4*)&cum[k][i0];
        const float4 dj = *(const float4*)&dlt[k][j0];
        const float* cip = (const float*)&ci;
        const float* djp = (const float*)&dj;
#pragma unroll
        for (int a = 0; a < 4; ++a)
#pragma unroll
            for (int c = 0; c < 4; ++c)
                m4[a][c] += cip[a] * djp[c];
    }
#pragma unroll
    for (int a = 0; a < 4; ++a)
#pragma unroll
        for (int c = 0; c < 4; ++c)
            Mm[i0 + a][j0 + c] = m4[a][c];
    __syncthreads();

    _Float16* out = LS + (size_t)(sl * B_SZ + b) * KP;
    if (t < D_SZ) out[t] = (_Float16)(seg[SEG][t] - seg[0][t]);   // level-1 inc
    if (t < KP - KDIM) out[KDIM + t] = (_Float16)0.0f;            // zero K pad
    if (tj >= ti) {
#pragma unroll
        for (int a = 0; a < 4; ++a) {
            const int i = i0 + a;
#pragma unroll
            for (int c = 0; c < 4; ++c) {
                const int j = j0 + c;
                if (j > i) {
                    const int p = 63 * i - (i * (i - 1)) / 2 + (j - i - 1);
                    out[D_SZ + p] = (_Float16)(0.5f * (m4[a][c] - Mm[j][i]));
                }
            }
        }
    }
}

// ---------------------------------------------------------------------------
// GEMM, 256x256 tile / BK=64 / 8 waves, 32x32x16 MFMA, phase-split schedule,
// counted vmcnt (never 0 in steady state), raw s_barrier, setprio, XOR-swizzle.
//
// Grid = EXACTLY 1024 blocks (32x32 main tiles over N=8192) = 4.0 rounds on
// 256 CUs (no tail). The 32 extra tiles of the b2/pad column strip (by=32,
// cols 8192..8447, only 64 stored) are folded into 32 "long" blocks (one per
// bx, x = 33*bx, spread across XCDs) that run a second tile iteration.
//
// LDS: 2 region-cycled buffers x (A 32KB + B 32KB) = 128 KiB.
// K-half block (256 rows x 32 k): 128 lines of 128B; line q holds rows 2q,2q+1;
// slot s (8 x 16B) for (p=row&1, chunk j) = (p*4+j) ^ (q&7).
// Staging: distance-2 prefetch. S1(t+1)@P0, S0(t+2)@P2; vmcnt(8) at P1/P3 ends.
// ---------------------------------------------------------------------------
#define GLDS(SRC, DST) __builtin_amdgcn_global_load_lds(                        \
    (__attribute__((address_space(1))) void*)(SRC),                             \
    (__attribute__((address_space(3))) void*)(DST), 16, 0, 0)

#define STAGE(KT, KK, BUF) do {                                                 \
    const unsigned short* _sa = Asrc + (size_t)(KT) * 64 + (KK) * 32;           \
    const unsigned short* _sb = Bsrc + (size_t)(KT) * 64 + (KK) * 32;           \
    unsigned short* _d = ldst + (BUF) * 32768 + (KK) * 8192;                    \
    GLDS(_sa,                  _d);                                             \
    GLDS(_sa + (size_t)128*KP, _d + 4096);                                      \
    GLDS(_sb,                  _d + 16384);                                     \
    GLDS(_sb + (size_t)128*KP, _d + 20480);                                     \
} while (0)

#define BAR() do { __builtin_amdgcn_s_barrier(); __builtin_amdgcn_sched_barrier(0); } while (0)

#define VMW_(N) asm volatile("s_waitcnt vmcnt(" #N ")" ::: "memory")
#define VMW(N) VMW_(N)

#define MFMA32(A, Bf, Cv) __builtin_amdgcn_mfma_f32_32x32x16_f16((A), (Bf), (Cv), 0, 0, 0)

// a0/a1 = rowblocks (MH*2+0/1) at s=0; a2/a3 same at s=1
#define LDA(MH, KK) do {                                                        \
    a0 = *(const f16x8*)(aC + (KK) * 8192 + (wm4 + (MH) * 2 + 0) * 1024 + fo);  \
    a1 = *(const f16x8*)(aC + (KK) * 8192 + (wm4 + (MH) * 2 + 1) * 1024 + fo);  \
    a2 = *(const f16x8*)(aC + (KK) * 8192 + (wm4 + (MH) * 2 + 0) * 1024 + (fo ^ 16)); \
    a3 = *(const f16x8*)(aC + (KK) * 8192 + (wm4 + (MH) * 2 + 1) * 1024 + (fo ^ 16)); \
} while (0)

// b0/b1 = colblocks 0/1 at s=0; b2/b3 at s=1
#define LDB(KK) do {                                                            \
    b0 = *(const f16x8*)(bC + (KK) * 8192 + (wn2 + 0) * 1024 + fo);             \
    b1 = *(const f16x8*)(bC + (KK) * 8192 + (wn2 + 1) * 1024 + fo);             \
    b2 = *(const f16x8*)(bC + (KK) * 8192 + (wn2 + 0) * 1024 + (fo ^ 16));      \
    b3 = *(const f16x8*)(bC + (KK) * 8192 + (wn2 + 1) * 1024 + (fo ^ 16));      \
} while (0)

#define MFMA8(MH) do {                                                          \
    __builtin_amdgcn_s_setprio(1);                                              \
    acc[(MH)*2+0][0] = MFMA32(a0, b0, acc[(MH)*2+0][0]);                        \
    acc[(MH)*2+0][1] = MFMA32(a0, b1, acc[(MH)*2+0][1]);                        \
    acc[(MH)*2+1][0] = MFMA32(a1, b0, acc[(MH)*2+1][0]);                        \
    acc[(MH)*2+1][1] = MFMA32(a1, b1, acc[(MH)*2+1][1]);                        \
    acc[(MH)*2+0][0] = MFMA32(a2, b2, acc[(MH)*2+0][0]);                        \
    acc[(MH)*2+0][1] = MFMA32(a2, b3, acc[(MH)*2+0][1]);                        \
    acc[(MH)*2+1][0] = MFMA32(a3, b2, acc[(MH)*2+1][0]);                        \
    acc[(MH)*2+1][1] = MFMA32(a3, b3, acc[(MH)*2+1][1]);                        \
    __builtin_amdgcn_s_setprio(0);                                              \
} while (0)

// One K-tile: 4 phases (K-half x M-half), 8 MFMA each.
#define TILE_BODY(TT, CUR, DOS1, DOS0, V1, V2) do {                             \
    const unsigned short* aC = ldsu + (CUR) * 32768;                            \
    const unsigned short* bC = aC + 16384;                                      \
    /* P0: Ka reads, stage S1(t+1) -> Kb(buf^1) */                              \
    if (DOS1) { STAGE((TT) + 1, 1, (CUR) ^ 1); }                                \
    LDB(0); LDA(0, 0);                                                          \
    BAR(); MFMA8(0); BAR();                                                     \
    /* P1 */                                                                    \
    LDA(1, 0);                                                                  \
    BAR(); MFMA8(1); VMW(V1); BAR();                                            \
    /* P2: Kb reads, stage S0(t+2) -> Ka(buf) */                                \
    if (DOS0) { STAGE((TT) + 2, 0, (CUR)); }                                    \
    LDB(1); LDA(0, 1);                                                          \
    BAR(); MFMA8(0); BAR();                                                     \
    /* P3 */                                                                    \
    LDA(1, 1);                                                                  \
    BAR(); MFMA8(1); VMW(V2); BAR();                                            \
} while (0)

__global__ __launch_bounds__(512, 2) void gemm256(const unsigned short* __restrict__ A,
                                                  const unsigned short* __restrict__ Bm,
                                                  _Float16* __restrict__ C) {
    __shared__ __align__(16) unsigned short ldsu[65536];    // 128 KiB
    const int t = threadIdx.x;

    // XCD swizzle over 1024 = 8*128: each XCD gets 128 consecutive x
    // -> bx in [xcd*4, xcd*4+4), by = x & 31 (A-panel L2-resident per XCD).
    const int wg = blockIdx.x;
    const int x  = (wg & 7) * 128 + (wg >> 3);
    const int bx = x >> 5, by0 = x & 31;
    const int nit = (by0 == bx) ? 2 : 1;     // 32 long blocks take the by=32 strip
    const int tileM = bx * 256;

    // staging source (pre-swizzled global address; LDS dest stays linear)
    const int q7s = (t >> 3) & 7;
    const int u   = (t & 7) ^ q7s;
    const int strow = ((t >> 3) << 1) + (u >> 2);   // row within 128-row round
    const int stcol = (u & 3) << 3;                 // element within 32-elem K-half
    const unsigned short* Asrc = A + (size_t)(tileM + strow) * KP + stcol;
    unsigned short* ldst = ldsu + t * 8;

    // fragment read addressing (32x32x16: row = lane&31, k-chunk = lane>>5)
    const int lane = t & 63, w = t >> 6;
    const int wm = w >> 2, wn = w & 3;              // 2M x 4N waves
    const int wm4 = wm * 4, wn2 = wn * 2;
    const int lrow = lane & 31, cc = lane >> 5;
    const int ql = lrow >> 1, pp = lrow & 1;
    const int fo = ql * 64 + ((((pp << 2) | cc) ^ (ql & 7)) << 3);

#pragma unroll 1
    for (int it = 0; it < nit; ++it) {
        const int tileN = (it == 0 ? by0 : 32) * 256;
        const unsigned short* Bsrc = Bm + (size_t)(tileN + strow) * KP + stcol;

        f32x16 acc[4][2] = {};
        f16x8 a0, a1, a2, a3, b0, b1, b2, b3;

        // prologue: S0(0)->Ka(b0), S1(0)->Kb(b0), S0(1)->Ka(b1); S0(0) visible
        STAGE(0, 0, 0);
        STAGE(0, 1, 0);
        STAGE(1, 0, 1);
        VMW(8);
        BAR();

        int cur = 0;
#pragma unroll 1
        for (int tt = 0; tt < NT - 2; ++tt) {
            TILE_BODY(tt, cur, 1, 1, 8, 8);
            cur ^= 1;
        }
        TILE_BODY(NT - 2, cur, 1, 0, 8, 4);
        cur ^= 1;
        TILE_BODY(NT - 1, cur, 0, 0, 0, 0);

        // C/D layout (32x32): col = lane&31, row = (reg&3) + 8*(reg>>2) + 4*(lane>>5)
#pragma unroll
        for (int rb = 0; rb < 4; ++rb) {
            const int rbase = tileM + wm * 128 + rb * 32 + cc * 4;
#pragma unroll
            for (int cb = 0; cb < 2; ++cb) {
                const int col = tileN + wn * 64 + cb * 32 + lrow;
                if (col < GSTR) {
#pragma unroll
                    for (int rg = 0; rg < 4; ++rg)
#pragma unroll
                        for (int rr = 0; rr < 4; ++rr)
                            C[(size_t)(rbase + rg * 8 + rr) * GSTR + col] =
                                (_Float16)acc[rb][cb][rg * 4 + rr];
                }
            }
        }
    }
}

// ---------------------------------------------------------------------------
// RK4 scan, ONE barrier per stage. One block (4 waves) per batch element.
// G column layout n = d*128 + m (row stride GSTR): thread (w, lane) reads
// m = w*32..w*32+31 at d = lane as 4 contiguous 16B vector loads.
// Serial FMA chains split into 4 independent accumulators (ILP).
// ---------------------------------------------------------------------------
__global__ __launch_bounds__(256) void ode_chunk(const _Float16* __restrict__ G,
                                                 const float* __restrict__ W1,
                                                 const float* __restrict__ b1,
                                                 float* __restrict__ h_state) {
    const int b = blockIdx.x, t = threadIdx.x;
    const int lane = t & 63, w = t >> 6;
    const int j0 = w * 32 + (lane & 31);       // this thread's z index
    __shared__ float ysw[4][D_SZ];             // per-wave y copies
    __shared__ float part[2][4][D_SZ];         // double-buffered partials

    float w1c[D_SZ];                           // W1[:, j0]
#pragma unroll
    for (int dd = 0; dd < D_SZ; ++dd) w1c[dd] = W1[dd * MLP_SZ + j0];
    const float b1v = b1[j0];

    float hsv = h_state[b * H_SZ + lane];      // all waves (redundant)
    ysw[w][lane] = hsv;
    float k_st[4] = {0.f, 0.f, 0.f, 0.f};

    f16x8 pr[4];
    _Float16 b2pre;
    {
        const _Float16* Gr = G + (size_t)b * GSTR;    // s = 0
        const f16x8* gp = (const f16x8*)(Gr + lane * 128 + w * 32);
#pragma unroll
        for (int v = 0; v < 4; ++v) pr[v] = gp[v];
        b2pre = Gr[8192 + lane];
    }

#pragma unroll 1
    for (int s = 0; s < NC; ++s) {
        float gcur[32];
#pragma unroll
        for (int v = 0; v < 4; ++v)
#pragma unroll
            for (int e = 0; e < 8; ++e) gcur[v * 8 + e] = (float)pr[v][e];
        const float b2cur = (float)b2pre;
        if (s + 1 < NC) {                      // prefetch next step (hidden by stages)
            const _Float16* Gr = G + (size_t)((s + 1) * B_SZ + b) * GSTR;
            const f16x8* gp = (const f16x8*)(Gr + lane * 128 + w * 32);
#pragma unroll
            for (int v = 0; v < 4; ++v) pr[v] = gp[v];
            b2pre = Gr[8192 + lane];
        }

#pragma unroll
        for (int st = 0; st < 4; ++st) {
            float ax = 0.f, ay = 0.f, az = 0.f, aw = 0.f;    // 4 indep chains
#pragma unroll
            for (int dd = 0; dd < D_SZ; dd += 4) {
                const float4 yv = *(const float4*)&ysw[w][dd];
                ax += yv.x * w1c[dd];
                ay += yv.y * w1c[dd + 1];
                az += yv.z * w1c[dd + 2];
                aw += yv.w * w1c[dd + 3];
            }
            const float xx = b1v + ((ax + ay) + (az + aw));
            const float ex = __expf(2.0f * xx);              // tanh(x)=1-2/(e^2x+1)
            const float z = 1.0f - 2.0f / (ex + 1.0f);
            float s0 = 0.f, s1 = 0.f, s2 = 0.f, s3 = 0.f;    // 4 indep chains
#pragma unroll
            for (int q = 0; q < 32; q += 4) {
                s0 += gcur[q]     * rlane(z, q);
                s1 += gcur[q + 1] * rlane(z, q + 1);
                s2 += gcur[q + 2] * rlane(z, q + 2);
                s3 += gcur[q + 3] * rlane(z, q + 3);
            }
            part[st & 1][w][lane] = (s0 + s1) + (s2 + s3);
            __syncthreads();                   // the ONE barrier per stage
            const float kv = b2cur + part[st & 1][0][lane] + part[st & 1][1][lane]
                           + part[st & 1][2][lane] + part[st & 1][3][lane];
            k_st[st] = kv;                     // every wave, identical
            if (st < 3) {
                float y = hsv;
                if (st == 0) y += 0.5f * kv;
                else if (st == 1) y += 0.5f * kv;
                else y += kv;
                ysw[w][lane] = y;              // own copy only
            }
        }
        hsv += (k_st[0] + 2.0f * k_st[1] + 2.0f * k_st[2] + k_st[3]) * (1.0f / 6.0f);
        ysw[w][lane] = hsv;                    // stage-0 y of next step
    }
    if (w == 0) h_state[b * H_SZ + lane] = hsv;
}

// ---------------------------------------------------------------------------
// out = hT @ W_out + b_out             <<<256, 64>>>
// ---------------------------------------------------------------------------
__global__ void out_kernel(const float* __restrict__ h_state, const float* __restrict__ W_out,
                           const float* __restrict__ b_out, float* __restrict__ out) {
    const int b = blockIdx.x, t = threadIdx.x;
    __shared__ float hh[H_SZ];
    hh[t] = h_state[b * H_SZ + t];
    __syncthreads();
    if (t < OUT_SZ) {
        float acc = b_out[t];
        for (int d = 0; d < H_SZ; ++d) acc += hh[d] * W_out[d * OUT_SZ + t];
        out[b * OUT_SZ + t] = acc;
    }
}

extern "C" void kernel_launch(void* const* d_in, const int* in_sizes, int n_in,
                              void* d_out, int out_size, void* d_ws, size_t ws_size,
                              hipStream_t stream) {
    (void)in_sizes; (void)n_in; (void)out_size; (void)ws_size;
    const float* X     = (const float*)d_in[0];
    const float* W_in  = (const float*)d_in[1];
    const float* b_in  = (const float*)d_in[2];
    const float* W1    = (const float*)d_in[3];
    const float* b1    = (const float*)d_in[4];
    const float* W2    = (const float*)d_in[5];
    const float* b2    = (const float*)d_in[6];
    const float* W_out = (const float*)d_in[7];
    const float* b_out = (const float*)d_in[8];
    float* out = (float*)d_out;

    // workspace layout (~205.6 MB total)
    char* ws = (char*)d_ws;
    size_t off = 0;
    auto take = [&](size_t bytes) { void* p = ws + off; off = (off + bytes + 255) & ~(size_t)255; return p; };
    _Float16* Bmat = (_Float16*)take((size_t)NB * KP * 2);      // 35.7 MB
    _Float16* LSc  = (_Float16*)take((size_t)MROWS * KP * 2);   // 34.6 MB
    _Float16* G    = (_Float16*)take((size_t)MROWS * GSTR * 2); // 135.3 MB
    float*    hst  = (float*)take((size_t)B_SZ * H_SZ * 4);     // 64 KB

    build_B<<<NB, 256, 0, stream>>>(W2, b2, Bmat);
    h0_kernel<<<B_SZ, H_SZ, 0, stream>>>(X, W_in, b_in, hst);

    for (int c = 0; c < NCHUNK; ++c) {
        logsig_kernel<<<dim3(B_SZ, NC), 256, 0, stream>>>(X, LSc, c * NC);
        gemm256<<<dim3(1024), 512, 0, stream>>>(
            (const unsigned short*)LSc, (const unsigned short*)Bmat, G);
        ode_chunk<<<B_SZ, 256, 0, stream>>>(G, W1, b1, hst);
    }
    out_kernel<<<B_SZ, H_SZ, 0, stream>>>(hst, W_out, b_out, out);
}

// Round 3
// 2072.273 us; speedup vs baseline: 1.3524x; 1.3524x over previous
//
#include <hip/hip_runtime.h>
#include <hip/hip_bf16.h>
#include <cstdint>
#include <cstddef>

// Problem constants
#define B_SZ   256
#define T_SZ   2049
#define D_SZ   64
#define H_SZ   64
#define MLP_SZ 128
#define NI_SZ  128
#define SEG    16          // (T-1)/NI
#define KDIM   2080        // L = D + D(D-1)/2
#define KP     2112        // padded K = 33*64 (BK=64 tiles)
#define OUT_SZ 10

// GEMM shapes
#define NC     32                  // intervals per chunk
#define NCHUNK (NI_SZ / NC)        // 4
#define MROWS  (NC * B_SZ)         // 8192 rows per chunk GEMM
#define NB     8448                // padded B rows = 33*256
#define GSTR   8256                // stored C cols (8192 G + 64 b2) = G row stride
#define NT     (KP / 64)           // 33 K-tiles

typedef _Float16 f16x8 __attribute__((ext_vector_type(8)));
typedef float    f32x4 __attribute__((ext_vector_type(4)));

__device__ __forceinline__ float rlane(float v, int l) {
    return __uint_as_float(__builtin_amdgcn_readlane(__float_as_uint(v), l));
}

// ---------------------------------------------------------------------------
// Build Bmat (fp16, [NB x KP] row-major), PERMUTED columns-of-G order:
//   row r' = d*128 + m  (d<64, m<128) holds W2[m][d*L + l]
//   rows 8192..8255: b2 row d  |  rows 8256..8447: zeros  |  k pad 2080..2111: 0
// ---------------------------------------------------------------------------
__global__ __launch_bounds__(256) void build_B(const float* __restrict__ W2,
                                               const float* __restrict__ b2,
                                               _Float16* __restrict__ Bm) {
    const int r = blockIdx.x, t = threadIdx.x;
    const float* src = nullptr;
    if (r < 8192) {
        const int d = r >> 7, m = r & 127;
        src = W2 + (size_t)m * (64 * KDIM) + (size_t)d * KDIM;
    } else if (r < 8256) {
        src = b2 + (size_t)(r - 8192) * KDIM;
    }
    _Float16* dst = Bm + (size_t)r * KP;
    for (int l = t; l < KP; l += 256)
        dst[l] = (src && l < KDIM) ? (_Float16)src[l] : (_Float16)0.0f;
}

// ---------------------------------------------------------------------------
// h0 = X[:,0,:] @ W_in + b_in          <<<256, 64>>>
// ---------------------------------------------------------------------------
__global__ void h0_kernel(const float* __restrict__ X, const float* __restrict__ W_in,
                          const float* __restrict__ b_in, float* __restrict__ h_state) {
    const int b = blockIdx.x, t = threadIdx.x;
    __shared__ float x0[D_SZ];
    if (t < D_SZ) x0[t] = X[(size_t)b * T_SZ * D_SZ + t];
    __syncthreads();
    float acc = b_in[t];
    for (int k = 0; k < D_SZ; ++k) acc += x0[k] * W_in[k * H_SZ + t];
    h_state[b * H_SZ + t] = acc;
}

// ---------------------------------------------------------------------------
// Depth-2 log-signature, tile-structured (4x4 register tiles, Lyndon order).
// grid (256, NC), 256 threads. Rows written with stride KP, pad zeroed.
// ---------------------------------------------------------------------------
__global__ __launch_bounds__(256) void logsig_kernel(const float* __restrict__ X,
                                                     _Float16* __restrict__ LS,
                                                     int n0) {
    const int b = blockIdx.x, sl = blockIdx.y, t = threadIdx.x;
    const int n = n0 + sl;
    __shared__ float seg[SEG + 1][D_SZ];
    __shared__ float cum[SEG][D_SZ];
    __shared__ float dlt[SEG][D_SZ];
    __shared__ float Mm[D_SZ][D_SZ + 1];   // +1 pad: transpose reads conflict-free

    const float* Xp = X + ((size_t)b * T_SZ + (size_t)n * SEG) * D_SZ;
    for (int i = t; i < (SEG + 1) * D_SZ / 4; i += 256)
        ((float4*)&seg[0][0])[i] = ((const float4*)Xp)[i];
    __syncthreads();
    for (int i = t; i < SEG * D_SZ; i += 256) {
        const int k = i >> 6, d = i & 63;
        cum[k][d] = seg[k][d] - seg[0][d];
        dlt[k][d] = seg[k + 1][d] - seg[k][d];
    }
    __syncthreads();

    const int ti = t >> 4, tj = t & 15;
    const int i0 = ti * 4, j0 = tj * 4;
    float m4[4][4] = {};
#pragma unroll
    for (int k = 0; k < SEG; ++k) {
        const float4 ci = *(const float4*)&cum[k][i0];
        const float4 dj = *(const float4*)&dlt[k][j0];
        const float* cip = (const float*)&ci;
        const float* djp = (const float*)&dj;
#pragma unroll
        for (int a = 0; a < 4; ++a)
#pragma unroll
            for (int c = 0; c < 4; ++c)
                m4[a][c] += cip[a] * djp[c];
    }
#pragma unroll
    for (int a = 0; a < 4; ++a)
#pragma unroll
        for (int c = 0; c < 4; ++c)
            Mm[i0 + a][j0 + c] = m4[a][c];
    __syncthreads();

    _Float16* out = LS + (size_t)(sl * B_SZ + b) * KP;
    if (t < D_SZ) out[t] = (_Float16)(seg[SEG][t] - seg[0][t]);   // level-1 inc
    if (t < KP - KDIM) out[KDIM + t] = (_Float16)0.0f;            // zero K pad
    if (tj >= ti) {
#pragma unroll
        for (int a = 0; a < 4; ++a) {
            const int i = i0 + a;
#pragma unroll
            for (int c = 0; c < 4; ++c) {
                const int j = j0 + c;
                if (j > i) {
                    const int p = 63 * i - (i * (i - 1)) / 2 + (j - i - 1);
                    out[D_SZ + p] = (_Float16)(0.5f * (m4[a][c] - Mm[j][i]));
                }
            }
        }
    }
}

// ---------------------------------------------------------------------------
// GEMM, 256x256 tile / BK=64 / 8 waves, 16x16x32 MFMA (round-1 proven core:
// 0 bank conflicts, no spill), phase-split schedule with counted vmcnt,
// raw s_barrier, setprio, XOR-swizzled LDS.
//
// Grid = EXACTLY 1024 blocks = 4.0 rounds on 256 CUs. The 33rd column strip
// (b2/pad, cols 8192..8447) is folded into 32 "long" blocks that run TWO
// tiles, and those are mapped to wg 0..31 so they DISPATCH FIRST:
//   32 CUs run {2T long + 2 short} = 4T, 224 CUs run 4 short = 4T
// -> makespan 4T (vs 5T for the naive 1056-block grid).
//
// LDS: 2 region-cycled buffers x (A 32KB + B 32KB) = 128 KiB.
// K-half block (256 rows x 32 k): 128 lines of 128B; line q holds rows 2q,2q+1;
// slot s (8 x 16B) for (p=row&1, chunk j) = (p*4+j) ^ (q&7).
// Staging: distance-2 prefetch. S1(t+1)@P0, S0(t+2)@P2; vmcnt(8) at P1/P3 ends.
// ---------------------------------------------------------------------------
#define GLDS(SRC, DST) __builtin_amdgcn_global_load_lds(                        \
    (__attribute__((address_space(1))) void*)(SRC),                             \
    (__attribute__((address_space(3))) void*)(DST), 16, 0, 0)

#define STAGE(KT, KK, BUF) do {                                                 \
    const unsigned short* _sa = Asrc + (size_t)(KT) * 64 + (KK) * 32;           \
    const unsigned short* _sb = Bsrc + (size_t)(KT) * 64 + (KK) * 32;           \
    unsigned short* _d = ldst + (BUF) * 32768 + (KK) * 8192;                    \
    GLDS(_sa,                  _d);                                             \
    GLDS(_sa + (size_t)128*KP, _d + 4096);                                      \
    GLDS(_sb,                  _d + 16384);                                     \
    GLDS(_sb + (size_t)128*KP, _d + 20480);                                     \
} while (0)

#define BAR() do { __builtin_amdgcn_s_barrier(); __builtin_amdgcn_sched_barrier(0); } while (0)

#define VMW_(N) asm volatile("s_waitcnt vmcnt(" #N ")" ::: "memory")
#define VMW(N) VMW_(N)

#define LOAD_A(KK, MB) do {                                                     \
    af0 = *(const f16x8*)(aC + (KK) * 8192 + ((MB) + 0) * 512);                 \
    af1 = *(const f16x8*)(aC + (KK) * 8192 + ((MB) + 1) * 512);                 \
    af2 = *(const f16x8*)(aC + (KK) * 8192 + ((MB) + 2) * 512);                 \
    af3 = *(const f16x8*)(aC + (KK) * 8192 + ((MB) + 3) * 512);                 \
} while (0)

#define LOAD_B(KK) do {                                                         \
    bg0 = *(const f16x8*)(bC + (KK) * 8192 + 0 * 512);                          \
    bg1 = *(const f16x8*)(bC + (KK) * 8192 + 1 * 512);                          \
    bg2 = *(const f16x8*)(bC + (KK) * 8192 + 2 * 512);                          \
    bg3 = *(const f16x8*)(bC + (KK) * 8192 + 3 * 512);                          \
} while (0)

#define MFMA16(MB) do {                                                         \
    __builtin_amdgcn_s_setprio(1);                                              \
    acc[(MB)+0][0] = __builtin_amdgcn_mfma_f32_16x16x32_f16(af0, bg0, acc[(MB)+0][0], 0, 0, 0); \
    acc[(MB)+0][1] = __builtin_amdgcn_mfma_f32_16x16x32_f16(af0, bg1, acc[(MB)+0][1], 0, 0, 0); \
    acc[(MB)+1][0] = __builtin_amdgcn_mfma_f32_16x16x32_f16(af1, bg0, acc[(MB)+1][0], 0, 0, 0); \
    acc[(MB)+1][1] = __builtin_amdgcn_mfma_f32_16x16x32_f16(af1, bg1, acc[(MB)+1][1], 0, 0, 0); \
    acc[(MB)+0][2] = __builtin_amdgcn_mfma_f32_16x16x32_f16(af0, bg2, acc[(MB)+0][2], 0, 0, 0); \
    acc[(MB)+0][3] = __builtin_amdgcn_mfma_f32_16x16x32_f16(af0, bg3, acc[(MB)+0][3], 0, 0, 0); \
    acc[(MB)+1][2] = __builtin_amdgcn_mfma_f32_16x16x32_f16(af1, bg2, acc[(MB)+1][2], 0, 0, 0); \
    acc[(MB)+1][3] = __builtin_amdgcn_mfma_f32_16x16x32_f16(af1, bg3, acc[(MB)+1][3], 0, 0, 0); \
    acc[(MB)+2][0] = __builtin_amdgcn_mfma_f32_16x16x32_f16(af2, bg0, acc[(MB)+2][0], 0, 0, 0); \
    acc[(MB)+2][1] = __builtin_amdgcn_mfma_f32_16x16x32_f16(af2, bg1, acc[(MB)+2][1], 0, 0, 0); \
    acc[(MB)+3][0] = __builtin_amdgcn_mfma_f32_16x16x32_f16(af3, bg0, acc[(MB)+3][0], 0, 0, 0); \
    acc[(MB)+3][1] = __builtin_amdgcn_mfma_f32_16x16x32_f16(af3, bg1, acc[(MB)+3][1], 0, 0, 0); \
    acc[(MB)+2][2] = __builtin_amdgcn_mfma_f32_16x16x32_f16(af2, bg2, acc[(MB)+2][2], 0, 0, 0); \
    acc[(MB)+2][3] = __builtin_amdgcn_mfma_f32_16x16x32_f16(af2, bg3, acc[(MB)+2][3], 0, 0, 0); \
    acc[(MB)+3][2] = __builtin_amdgcn_mfma_f32_16x16x32_f16(af3, bg2, acc[(MB)+3][2], 0, 0, 0); \
    acc[(MB)+3][3] = __builtin_amdgcn_mfma_f32_16x16x32_f16(af3, bg3, acc[(MB)+3][3], 0, 0, 0); \
    __builtin_amdgcn_s_setprio(0);                                              \
} while (0)

// One K-tile: 4 phases (K-half x M-half), 16 MFMA each.
#define TILE_BODY(TT, CUR, DOS1, DOS0, V1, V2) do {                             \
    const unsigned short* aC = aP + (CUR) * 32768;                              \
    const unsigned short* bC = bP + (CUR) * 32768;                              \
    /* P0: Ka reads, stage S1(t+1) -> Kb(buf^1) */                              \
    if (DOS1) { STAGE((TT) + 1, 1, (CUR) ^ 1); }                                \
    LOAD_B(0); LOAD_A(0, 0);                                                    \
    BAR(); MFMA16(0); BAR();                                                    \
    /* P1 */                                                                    \
    LOAD_A(0, 4);                                                               \
    BAR(); MFMA16(4); VMW(V1); BAR();                                           \
    /* P2: Kb reads, stage S0(t+2) -> Ka(buf) */                                \
    if (DOS0) { STAGE((TT) + 2, 0, (CUR)); }                                    \
    LOAD_B(1); LOAD_A(1, 0);                                                    \
    BAR(); MFMA16(0); BAR();                                                    \
    /* P3 */                                                                    \
    LOAD_A(1, 4);                                                               \
    BAR(); MFMA16(4); VMW(V2); BAR();                                           \
} while (0)

__global__ __launch_bounds__(512, 2) void gemm256(const unsigned short* __restrict__ A,
                                                  const unsigned short* __restrict__ Bm,
                                                  _Float16* __restrict__ C) {
    __shared__ __align__(16) unsigned short lds[65536];    // 128 KiB
    const int t = threadIdx.x;

    // Block mapping (1024 blocks):
    //   wg 0..31   : long blocks, bx = (wg&7)*4 + wg>>3, tiles (bx,bx) + (bx,32)
    //   wg 32..1023: xcd = wg&7 owns bx in [4*xcd, 4*xcd+4); idx enumerates
    //                4 bx x 31 by (skipping by==bx, the diagonal)
    const int wg = blockIdx.x;
    int bx, by0, nit;
    if (wg < 32) {
        bx = (wg & 7) * 4 + (wg >> 3);
        by0 = bx;
        nit = 2;
    } else {
        const int idx = (wg - 32) >> 3;
        bx = (wg & 7) * 4 + idx / 31;
        const int byi = idx % 31;
        by0 = byi + (byi >= bx ? 1 : 0);
        nit = 1;
    }
    const int tileM = bx * 256;

    // staging source (pre-swizzled global address; LDS dest stays linear)
    const int q7s = (t >> 3) & 7;
    const int u   = (t & 7) ^ q7s;
    const int strow = ((t >> 3) << 1) + (u >> 2);   // row within 128-row round
    const int stcol = (u & 3) << 3;                 // element within 32-elem K-half
    const unsigned short* Asrc = A + (size_t)(tileM + strow) * KP + stcol;
    unsigned short* ldst = lds + t * 8;

    // fragment read addressing (swizzled)
    const int lane = t & 63, w = t >> 6;
    const int wm = w >> 2, wn = w & 3;              // 2M x 4N waves
    const int frow = lane & 15, j4 = lane >> 4;
    const int fr2 = frow >> 1;
    const int slot = (((frow & 1) << 2) | j4) ^ fr2;
    const unsigned short* aP = lds + wm * 4096 + fr2 * 64 + slot * 8;
    const unsigned short* bP = lds + 16384 + wn * 2048 + fr2 * 64 + slot * 8;

#pragma unroll 1
    for (int it = 0; it < nit; ++it) {
        const int tileN = (it == 0 ? by0 : 32) * 256;
        const unsigned short* Bsrc = Bm + (size_t)(tileN + strow) * KP + stcol;

        f32x4 acc[8][4] = {};
        f16x8 af0, af1, af2, af3, bg0, bg1, bg2, bg3;

        // prologue: S0(0)->Ka(b0), S1(0)->Kb(b0), S0(1)->Ka(b1); S0(0) visible
        STAGE(0, 0, 0);
        STAGE(0, 1, 0);
        STAGE(1, 0, 1);
        VMW(8);
        BAR();

        int cur = 0;
#pragma unroll 1
        for (int tt = 0; tt < NT - 2; ++tt) {
            TILE_BODY(tt, cur, 1, 1, 8, 8);
            cur ^= 1;
        }
        TILE_BODY(NT - 2, cur, 1, 0, 8, 4);
        cur ^= 1;
        TILE_BODY(NT - 1, cur, 0, 0, 0, 0);

        // C/D layout: col = lane&15, row = (lane>>4)*4 + reg. Store cols < GSTR.
        const int erow = j4 << 2;
#pragma unroll
        for (int mi = 0; mi < 8; ++mi) {
            const int grow = tileM + wm * 128 + mi * 16 + erow;
#pragma unroll
            for (int ni = 0; ni < 4; ++ni) {
                const int gcol = tileN + wn * 64 + ni * 16 + frow;
                if (gcol < GSTR) {
                    _Float16* cp = C + (size_t)grow * GSTR + gcol;
#pragma unroll
                    for (int r = 0; r < 4; ++r)
                        cp[(size_t)r * GSTR] = (_Float16)acc[mi][ni][r];
                }
            }
        }
    }
}

// ---------------------------------------------------------------------------
// RK4 scan, ONE barrier per stage. One block (4 waves) per batch element.
// G column layout n = d*128 + m (row stride GSTR): thread (w, lane) reads
// m = w*32..w*32+31 at d = lane as 4 contiguous 16B vector loads.
// Serial FMA chains split into 4 independent accumulators (ILP).
// ---------------------------------------------------------------------------
__global__ __launch_bounds__(256) void ode_chunk(const _Float16* __restrict__ G,
                                                 const float* __restrict__ W1,
                                                 const float* __restrict__ b1,
                                                 float* __restrict__ h_state) {
    const int b = blockIdx.x, t = threadIdx.x;
    const int lane = t & 63, w = t >> 6;
    const int j0 = w * 32 + (lane & 31);       // this thread's z index
    __shared__ float ysw[4][D_SZ];             // per-wave y copies
    __shared__ float part[2][4][D_SZ];         // double-buffered partials

    float w1c[D_SZ];                           // W1[:, j0]
#pragma unroll
    for (int dd = 0; dd < D_SZ; ++dd) w1c[dd] = W1[dd * MLP_SZ + j0];
    const float b1v = b1[j0];

    float hsv = h_state[b * H_SZ + lane];      // all waves (redundant)
    ysw[w][lane] = hsv;
    float k_st[4] = {0.f, 0.f, 0.f, 0.f};

    f16x8 pr[4];
    _Float16 b2pre;
    {
        const _Float16* Gr = G + (size_t)b * GSTR;    // s = 0
        const f16x8* gp = (const f16x8*)(Gr + lane * 128 + w * 32);
#pragma unroll
        for (int v = 0; v < 4; ++v) pr[v] = gp[v];
        b2pre = Gr[8192 + lane];
    }

#pragma unroll 1
    for (int s = 0; s < NC; ++s) {
        float gcur[32];
#pragma unroll
        for (int v = 0; v < 4; ++v)
#pragma unroll
            for (int e = 0; e < 8; ++e) gcur[v * 8 + e] = (float)pr[v][e];
        const float b2cur = (float)b2pre;
        if (s + 1 < NC) {                      // prefetch next step (hidden by stages)
            const _Float16* Gr = G + (size_t)((s + 1) * B_SZ + b) * GSTR;
            const f16x8* gp = (const f16x8*)(Gr + lane * 128 + w * 32);
#pragma unroll
            for (int v = 0; v < 4; ++v) pr[v] = gp[v];
            b2pre = Gr[8192 + lane];
        }

#pragma unroll
        for (int st = 0; st < 4; ++st) {
            float ax = 0.f, ay = 0.f, az = 0.f, aw = 0.f;    // 4 indep chains
#pragma unroll
            for (int dd = 0; dd < D_SZ; dd += 4) {
                const float4 yv = *(const float4*)&ysw[w][dd];
                ax += yv.x * w1c[dd];
                ay += yv.y * w1c[dd + 1];
                az += yv.z * w1c[dd + 2];
                aw += yv.w * w1c[dd + 3];
            }
            const float xx = b1v + ((ax + ay) + (az + aw));
            const float ex = __expf(2.0f * xx);              // tanh(x)=1-2/(e^2x+1)
            const float z = 1.0f - 2.0f / (ex + 1.0f);
            float s0 = 0.f, s1 = 0.f, s2 = 0.f, s3 = 0.f;    // 4 indep chains
#pragma unroll
            for (int q = 0; q < 32; q += 4) {
                s0 += gcur[q]     * rlane(z, q);
                s1 += gcur[q + 1] * rlane(z, q + 1);
                s2 += gcur[q + 2] * rlane(z, q + 2);
                s3 += gcur[q + 3] * rlane(z, q + 3);
            }
            part[st & 1][w][lane] = (s0 + s1) + (s2 + s3);
            __syncthreads();                   // the ONE barrier per stage
            const float kv = b2cur + part[st & 1][0][lane] + part[st & 1][1][lane]
                           + part[st & 1][2][lane] + part[st & 1][3][lane];
            k_st[st] = kv;                     // every wave, identical
            if (st < 3) {
                float y = hsv;
                if (st == 0) y += 0.5f * kv;
                else if (st == 1) y += 0.5f * kv;
                else y += kv;
                ysw[w][lane] = y;              // own copy only
            }
        }
        hsv += (k_st[0] + 2.0f * k_st[1] + 2.0f * k_st[2] + k_st[3]) * (1.0f / 6.0f);
        ysw[w][lane] = hsv;                    // stage-0 y of next step
    }
    if (w == 0) h_state[b * H_SZ + lane] = hsv;
}

// ---------------------------------------------------------------------------
// out = hT @ W_out + b_out             <<<256, 64>>>
// ---------------------------------------------------------------------------
__global__ void out_kernel(const float* __restrict__ h_state, const float* __restrict__ W_out,
                           const float* __restrict__ b_out, float* __restrict__ out) {
    const int b = blockIdx.x, t = threadIdx.x;
    __shared__ float hh[H_SZ];
    hh[t] = h_state[b * H_SZ + t];
    __syncthreads();
    if (t < OUT_SZ) {
        float acc = b_out[t];
        for (int d = 0; d < H_SZ; ++d) acc += hh[d] * W_out[d * OUT_SZ + t];
        out[b * OUT_SZ + t] = acc;
    }
}

extern "C" void kernel_launch(void* const* d_in, const int* in_sizes, int n_in,
                              void* d_out, int out_size, void* d_ws, size_t ws_size,
                              hipStream_t stream) {
    (void)in_sizes; (void)n_in; (void)out_size; (void)ws_size;
    const float* X     = (const float*)d_in[0];
    const float* W_in  = (const float*)d_in[1];
    const float* b_in  = (const float*)d_in[2];
    const float* W1    = (const float*)d_in[3];
    const float* b1    = (const float*)d_in[4];
    const float* W2    = (const float*)d_in[5];
    const float* b2    = (const float*)d_in[6];
    const float* W_out = (const float*)d_in[7];
    const float* b_out = (const float*)d_in[8];
    float* out = (float*)d_out;

    // workspace layout (~205.6 MB total)
    char* ws = (char*)d_ws;
    size_t off = 0;
    auto take = [&](size_t bytes) { void* p = ws + off; off = (off + bytes + 255) & ~(size_t)255; return p; };
    _Float16* Bmat = (_Float16*)take((size_t)NB * KP * 2);      // 35.7 MB
    _Float16* LSc  = (_Float16*)take((size_t)MROWS * KP * 2);   // 34.6 MB
    _Float16* G    = (_Float16*)take((size_t)MROWS * GSTR * 2); // 135.3 MB
    float*    hst  = (float*)take((size_t)B_SZ * H_SZ * 4);     // 64 KB

    build_B<<<NB, 256, 0, stream>>>(W2, b2, Bmat);
    h0_kernel<<<B_SZ, H_SZ, 0, stream>>>(X, W_in, b_in, hst);

    for (int c = 0; c < NCHUNK; ++c) {
        logsig_kernel<<<dim3(B_SZ, NC), 256, 0, stream>>>(X, LSc, c * NC);
        gemm256<<<dim3(1024), 512, 0, stream>>>(
            (const unsigned short*)LSc, (const unsigned short*)Bmat, G);
        ode_chunk<<<B_SZ, 256, 0, stream>>>(G, W1, b1, hst);
    }
    out_kernel<<<B_SZ, H_SZ, 0, stream>>>(hst, W_out, b_out, out);
}

// Round 5
// 1975.060 us; speedup vs baseline: 1.4190x; 1.0492x over previous
//
#include <hip/hip_runtime.h>
#include <hip/hip_bf16.h>
#include <cstdint>
#include <cstddef>

// Problem constants
#define B_SZ   256
#define T_SZ   2049
#define D_SZ   64
#define H_SZ   64
#define MLP_SZ 128
#define NI_SZ  128
#define SEG    16          // (T-1)/NI
#define KDIM   2080        // L = D + D(D-1)/2
#define KP     2112        // padded K = 33*64 (BK=64 tiles)
#define OUT_SZ 10

// GEMM shapes
#define NC     32                  // intervals per chunk
#define NCHUNK (NI_SZ / NC)        // 4
#define MROWS  (NC * B_SZ)         // 8192 rows per chunk GEMM
#define NB     8448                // padded B rows = 33*256
#define GSTR   8256                // stored C cols (8192 G + 64 b2) = G row stride
#define NT     (KP / 64)           // 33 K-tiles

typedef _Float16 f16x8 __attribute__((ext_vector_type(8)));
typedef float    f32x4 __attribute__((ext_vector_type(4)));

__device__ __forceinline__ float rlane(float v, int l) {
    return __uint_as_float(__builtin_amdgcn_readlane(__float_as_uint(v), l));
}

// ---------------------------------------------------------------------------
// Build Bmat (fp16, [NB x KP] row-major), PERMUTED columns-of-G order:
//   row r' = d*128 + m  (d<64, m<128) holds W2[m][d*L + l]
//   rows 8192..8255: b2 row d  |  rows 8256..8447: zeros  |  k pad 2080..2111: 0
// ---------------------------------------------------------------------------
__global__ __launch_bounds__(256) void build_B(const float* __restrict__ W2,
                                               const float* __restrict__ b2,
                                               _Float16* __restrict__ Bm) {
    const int r = blockIdx.x, t = threadIdx.x;
    const float* src = nullptr;
    if (r < 8192) {
        const int d = r >> 7, m = r & 127;
        src = W2 + (size_t)m * (64 * KDIM) + (size_t)d * KDIM;
    } else if (r < 8256) {
        src = b2 + (size_t)(r - 8192) * KDIM;
    }
    _Float16* dst = Bm + (size_t)r * KP;
    for (int l = t; l < KP; l += 256)
        dst[l] = (src && l < KDIM) ? (_Float16)src[l] : (_Float16)0.0f;
}

// ---------------------------------------------------------------------------
// h0 = X[:,0,:] @ W_in + b_in          <<<256, 64>>>
// ---------------------------------------------------------------------------
__global__ void h0_kernel(const float* __restrict__ X, const float* __restrict__ W_in,
                          const float* __restrict__ b_in, float* __restrict__ h_state) {
    const int b = blockIdx.x, t = threadIdx.x;
    __shared__ float x0[D_SZ];
    if (t < D_SZ) x0[t] = X[(size_t)b * T_SZ * D_SZ + t];
    __syncthreads();
    float acc = b_in[t];
    for (int k = 0; k < D_SZ; ++k) acc += x0[k] * W_in[k * H_SZ + t];
    h_state[b * H_SZ + t] = acc;
}

// ---------------------------------------------------------------------------
// Depth-2 log-signature, tile-structured (4x4 register tiles, Lyndon order).
// grid (256, NC), 256 threads. Rows written with stride KP, pad zeroed.
// ---------------------------------------------------------------------------
__global__ __launch_bounds__(256) void logsig_kernel(const float* __restrict__ X,
                                                     _Float16* __restrict__ LS,
                                                     int n0) {
    const int b = blockIdx.x, sl = blockIdx.y, t = threadIdx.x;
    const int n = n0 + sl;
    __shared__ float seg[SEG + 1][D_SZ];
    __shared__ float cum[SEG][D_SZ];
    __shared__ float dlt[SEG][D_SZ];
    __shared__ float Mm[D_SZ][D_SZ + 1];   // +1 pad: transpose reads conflict-free

    const float* Xp = X + ((size_t)b * T_SZ + (size_t)n * SEG) * D_SZ;
    for (int i = t; i < (SEG + 1) * D_SZ / 4; i += 256)
        ((float4*)&seg[0][0])[i] = ((const float4*)Xp)[i];
    __syncthreads();
    for (int i = t; i < SEG * D_SZ; i += 256) {
        const int k = i >> 6, d = i & 63;
        cum[k][d] = seg[k][d] - seg[0][d];
        dlt[k][d] = seg[k + 1][d] - seg[k][d];
    }
    __syncthreads();

    const int ti = t >> 4, tj = t & 15;
    const int i0 = ti * 4, j0 = tj * 4;
    float m4[4][4] = {};
#pragma unroll
    for (int k = 0; k < SEG; ++k) {
        const float4 ci = *(const float4*)&cum[k][i0];
        const float4 dj = *(const float4*)&dlt[k][j0];
        const float* cip = (const float*)&ci;
        const float* djp = (const float*)&dj;
#pragma unroll
        for (int a = 0; a < 4; ++a)
#pragma unroll
            for (int c = 0; c < 4; ++c)
                m4[a][c] += cip[a] * djp[c];
    }
#pragma unroll
    for (int a = 0; a < 4; ++a)
#pragma unroll
        for (int c = 0; c < 4; ++c)
            Mm[i0 + a][j0 + c] = m4[a][c];
    __syncthreads();

    _Float16* out = LS + (size_t)(sl * B_SZ + b) * KP;
    if (t < D_SZ) out[t] = (_Float16)(seg[SEG][t] - seg[0][t]);   // level-1 inc
    if (t < KP - KDIM) out[KDIM + t] = (_Float16)0.0f;            // zero K pad
    if (tj >= ti) {
#pragma unroll
        for (int a = 0; a < 4; ++a) {
            const int i = i0 + a;
#pragma unroll
            for (int c = 0; c < 4; ++c) {
                const int j = j0 + c;
                if (j > i) {
                    const int p = 63 * i - (i * (i - 1)) / 2 + (j - i - 1);
                    out[D_SZ + p] = (_Float16)(0.5f * (m4[a][c] - Mm[j][i]));
                }
            }
        }
    }
}

// ---------------------------------------------------------------------------
// GEMM, 256x256 tile / BK=64 / 8 waves, 16x16x32 MFMA, ONE-PHASE REGISTER
// PIPELINING: each cluster issues the ds_reads for the NEXT cluster's MFMA
// into an alternating frag set, so LDS-read drain overlaps the matrix pipe
// and lgkmcnt before MFMA waits on cluster-old reads (free). One s_barrier
// per cluster. Safety: each cluster's reads are lgkm-complete before their
// consumer MFMA in the next cluster (compiler-inserted lgkmcnt), hence
// before that cluster's barrier; the overwriting STAGE is issued >=1
// barrier after that. sched_barrier(0) on BOTH sides of s_barrier pins
// the MFMA clusters (pure ops) inside their phase.
//
// STAGING FIX (round-4 bug): DOS0 must be 1 for ALL loop iterations --
// S0(NT-1) is staged at tt=NT-3.P2; the (tt < NT-3) guard skipped it and
// the last K-tile consumed stale LDS (absmax 5.75).
//
// LDS: 2 region-cycled buffers x (A 32KB + B 32KB) = 128 KiB.
// K-half block (256 rows x 32 k): 128 lines of 128B; line q holds rows 2q,2q+1;
// slot s (8 x 16B) for (p=row&1, chunk j) = (p*4+j) ^ (q&7). 0 bank conflicts.
// Staging: distance-2 prefetch; S1(t+1)@P0, S0(t+2)@P2. Visibility chain:
// VMW(4)@P1 -> S0(t+1) landed (issued t-1.P2), bar -> Ka' reads at t.P3 safe;
// VMW(4)@P3 -> S1(t+1) landed (issued t.P0), bar -> Kb reads at (t+1).P1 safe.
// Tail: NT-2 uses V2=0 (drain S1(NT-1)); prologue VMW(4).
// M=8192, N=8448 (cols >= 8256 computed, not stored), K=2112. grid 1056x512.
// ---------------------------------------------------------------------------
#define GLDS(SRC, DST) __builtin_amdgcn_global_load_lds(                        \
    (__attribute__((address_space(1))) void*)(SRC),                             \
    (__attribute__((address_space(3))) void*)(DST), 16, 0, 0)

#define STAGE(KT, KK, BUF) do {                                                 \
    const unsigned short* _sa = Asrc + (size_t)(KT) * 64 + (KK) * 32;           \
    const unsigned short* _sb = Bsrc + (size_t)(KT) * 64 + (KK) * 32;           \
    unsigned short* _d = ldst + (BUF) * 32768 + (KK) * 8192;                    \
    GLDS(_sa,                  _d);                                             \
    GLDS(_sa + (size_t)128*KP, _d + 4096);                                      \
    GLDS(_sb,                  _d + 16384);                                     \
    GLDS(_sb + (size_t)128*KP, _d + 20480);                                     \
} while (0)

#define BAR() do {                                                              \
    __builtin_amdgcn_sched_barrier(0);                                          \
    __builtin_amdgcn_s_barrier();                                               \
    __builtin_amdgcn_sched_barrier(0);                                          \
} while (0)

#define VMW_(N) asm volatile("s_waitcnt vmcnt(" #N ")" ::: "memory")
#define VMW(N) VMW_(N)

// read 4 A-frags (m-blocks MB..MB+3, K-half KK) into frag set S
#define RD_A(S, PTR, KK, MB) do {                                               \
    a##S##0 = *(const f16x8*)((PTR) + (KK) * 8192 + ((MB) + 0) * 512);          \
    a##S##1 = *(const f16x8*)((PTR) + (KK) * 8192 + ((MB) + 1) * 512);          \
    a##S##2 = *(const f16x8*)((PTR) + (KK) * 8192 + ((MB) + 2) * 512);          \
    a##S##3 = *(const f16x8*)((PTR) + (KK) * 8192 + ((MB) + 3) * 512);          \
} while (0)

// read 4 B-frags (K-half KK) into frag set S
#define RD_B(S, PTR, KK) do {                                                   \
    b##S##0 = *(const f16x8*)((PTR) + (KK) * 8192 + 0 * 512);                   \
    b##S##1 = *(const f16x8*)((PTR) + (KK) * 8192 + 1 * 512);                   \
    b##S##2 = *(const f16x8*)((PTR) + (KK) * 8192 + 2 * 512);                   \
    b##S##3 = *(const f16x8*)((PTR) + (KK) * 8192 + 3 * 512);                   \
} while (0)

#define MFMA16(MB, AS, BS) do {                                                 \
    __builtin_amdgcn_s_setprio(1);                                              \
    acc[(MB)+0][0] = __builtin_amdgcn_mfma_f32_16x16x32_f16(a##AS##0, b##BS##0, acc[(MB)+0][0], 0, 0, 0); \
    acc[(MB)+0][1] = __builtin_amdgcn_mfma_f32_16x16x32_f16(a##AS##0, b##BS##1, acc[(MB)+0][1], 0, 0, 0); \
    acc[(MB)+1][0] = __builtin_amdgcn_mfma_f32_16x16x32_f16(a##AS##1, b##BS##0, acc[(MB)+1][0], 0, 0, 0); \
    acc[(MB)+1][1] = __builtin_amdgcn_mfma_f32_16x16x32_f16(a##AS##1, b##BS##1, acc[(MB)+1][1], 0, 0, 0); \
    acc[(MB)+0][2] = __builtin_amdgcn_mfma_f32_16x16x32_f16(a##AS##0, b##BS##2, acc[(MB)+0][2], 0, 0, 0); \
    acc[(MB)+0][3] = __builtin_amdgcn_mfma_f32_16x16x32_f16(a##AS##0, b##BS##3, acc[(MB)+0][3], 0, 0, 0); \
    acc[(MB)+1][2] = __builtin_amdgcn_mfma_f32_16x16x32_f16(a##AS##1, b##BS##2, acc[(MB)+1][2], 0, 0, 0); \
    acc[(MB)+1][3] = __builtin_amdgcn_mfma_f32_16x16x32_f16(a##AS##1, b##BS##3, acc[(MB)+1][3], 0, 0, 0); \
    acc[(MB)+2][0] = __builtin_amdgcn_mfma_f32_16x16x32_f16(a##AS##2, b##BS##0, acc[(MB)+2][0], 0, 0, 0); \
    acc[(MB)+2][1] = __builtin_amdgcn_mfma_f32_16x16x32_f16(a##AS##2, b##BS##1, acc[(MB)+2][1], 0, 0, 0); \
    acc[(MB)+3][0] = __builtin_amdgcn_mfma_f32_16x16x32_f16(a##AS##3, b##BS##0, acc[(MB)+3][0], 0, 0, 0); \
    acc[(MB)+3][1] = __builtin_amdgcn_mfma_f32_16x16x32_f16(a##AS##3, b##BS##1, acc[(MB)+3][1], 0, 0, 0); \
    acc[(MB)+2][2] = __builtin_amdgcn_mfma_f32_16x16x32_f16(a##AS##2, b##BS##2, acc[(MB)+2][2], 0, 0, 0); \
    acc[(MB)+2][3] = __builtin_amdgcn_mfma_f32_16x16x32_f16(a##AS##2, b##BS##3, acc[(MB)+2][3], 0, 0, 0); \
    acc[(MB)+3][2] = __builtin_amdgcn_mfma_f32_16x16x32_f16(a##AS##3, b##BS##2, acc[(MB)+3][2], 0, 0, 0); \
    acc[(MB)+3][3] = __builtin_amdgcn_mfma_f32_16x16x32_f16(a##AS##3, b##BS##3, acc[(MB)+3][3], 0, 0, 0); \
    __builtin_amdgcn_s_setprio(0);                                              \
} while (0)

// One K-tile: 4 clusters, each {reads for NEXT cluster | MFMA current | bar}.
// Consumption: P0: set0 x hp0 (Ka, acc0-3)   reads: set1 <- Ka mb4-7
//              P1: set1 x hp0 (Ka, acc4-7)   reads: set0 <- Kb mb0-3, hp1 <- Kb B
//              P2: set0 x hp1 (Kb, acc0-3)   reads: set1 <- Kb mb4-7
//              P3: set1 x hp1 (Kb, acc4-7)   reads: set0 <- Ka' mb0-3, hp0 <- Ka' B
#define TILE_BODY(TT, CUR, DOS1, DOS0, RDN, V1, V2) do {                        \
    const unsigned short* aC = aP + (CUR) * 32768;                              \
    const unsigned short* bC = bP + (CUR) * 32768;                              \
    const unsigned short* aN = aP + ((CUR) ^ 1) * 32768;                        \
    const unsigned short* bN = bP + ((CUR) ^ 1) * 32768;                        \
    /* P0 */                                                                    \
    if (DOS1) { STAGE((TT) + 1, 1, (CUR) ^ 1); }                                \
    RD_A(1, aC, 0, 4);                                                          \
    MFMA16(0, 0, 0);                                                            \
    BAR();                                                                      \
    /* P1 */                                                                    \
    RD_A(0, aC, 1, 0);                                                          \
    RD_B(1, bC, 1);                                                             \
    MFMA16(4, 1, 0);                                                            \
    VMW(V1); BAR();                                                             \
    /* P2 */                                                                    \
    if (DOS0) { STAGE((TT) + 2, 0, (CUR)); }                                    \
    RD_A(1, aC, 1, 4);                                                          \
    MFMA16(0, 0, 1);                                                            \
    BAR();                                                                      \
    /* P3 */                                                                    \
    if (RDN) { RD_A(0, aN, 0, 0); RD_B(0, bN, 0); }                             \
    MFMA16(4, 1, 1);                                                            \
    VMW(V2); BAR();                                                             \
} while (0)

__global__ __launch_bounds__(512, 2) void gemm256(const unsigned short* __restrict__ A,
                                                  const unsigned short* __restrict__ Bm,
                                                  _Float16* __restrict__ C) {
    __shared__ __align__(16) unsigned short lds[65536];    // 128 KiB
    const int t = threadIdx.x;

    // XCD-bijective swizzle: 1056 = 8*132; xcd = wg&7 gets 132 consecutive x.
    const int wg = blockIdx.x;
    const int x  = (wg & 7) * 132 + (wg >> 3);
    const int bx = x / 33, by = x % 33;
    const int tileM = bx * 256, tileN = by * 256;

    // staging source (pre-swizzled global address; LDS dest stays linear)
    const int q7s = (t >> 3) & 7;
    const int u   = (t & 7) ^ q7s;
    const int strow = ((t >> 3) << 1) + (u >> 2);   // row within 128-row round
    const int stcol = (u & 3) << 3;                 // element within 32-elem K-half
    const unsigned short* Asrc = A  + (size_t)(tileM + strow) * KP + stcol;
    const unsigned short* Bsrc = Bm + (size_t)(tileN + strow) * KP + stcol;
    unsigned short* ldst = lds + t * 8;

    // fragment read addressing (swizzled)
    const int lane = t & 63, w = t >> 6;
    const int wm = w >> 2, wn = w & 3;              // 2M x 4N waves
    const int frow = lane & 15, j4 = lane >> 4;
    const int fr2 = frow >> 1;
    const int slot = (((frow & 1) << 2) | j4) ^ fr2;
    const unsigned short* aP = lds + wm * 4096 + fr2 * 64 + slot * 8;
    const unsigned short* bP = lds + 16384 + wn * 2048 + fr2 * 64 + slot * 8;

    f32x4 acc[8][4] = {};
    f16x8 a00, a01, a02, a03, a10, a11, a12, a13;
    f16x8 b00, b01, b02, b03, b10, b11, b12, b13;

    // prologue: S0(0)->Ka(b0), S1(0)->Kb(b0), S0(1)->Ka(b1).
    // VMW(4): S0(0)+S1(0) landed (only S0(1) outstanding); BAR -> visible.
    STAGE(0, 0, 0);
    STAGE(0, 1, 0);
    STAGE(1, 0, 1);
    VMW(4);
    BAR();
    RD_A(0, aP, 0, 0);     // tile0 Ka mb0-3
    RD_B(0, bP, 0);        // tile0 Ka B

    int cur = 0;
#pragma unroll 1
    for (int tt = 0; tt < NT - 2; ++tt) {
        TILE_BODY(tt, cur, 1, 1, 1, 4, 4);    // DOS0=1 ALWAYS: stages S0(2..NT-1)
        cur ^= 1;
    }
    TILE_BODY(NT - 2, cur, 1, 0, 1, 4, 0);
    cur ^= 1;
    TILE_BODY(NT - 1, cur, 0, 0, 0, 0, 0);

    // C/D layout: col = lane&15, row = (lane>>4)*4 + reg. Store cols < GSTR.
    const int erow = j4 << 2;
#pragma unroll
    for (int mi = 0; mi < 8; ++mi) {
        const int grow = tileM + wm * 128 + mi * 16 + erow;
#pragma unroll
        for (int ni = 0; ni < 4; ++ni) {
            const int gcol = tileN + wn * 64 + ni * 16 + frow;
            if (gcol < GSTR) {
                _Float16* cp = C + (size_t)grow * GSTR + gcol;
#pragma unroll
                for (int r = 0; r < 4; ++r)
                    cp[(size_t)r * GSTR] = (_Float16)acc[mi][ni][r];
            }
        }
    }
}

// ---------------------------------------------------------------------------
// RK4 scan, ONE barrier per stage. One block (4 waves) per batch element.
// G column layout n = d*128 + m (row stride GSTR): thread (w, lane) reads
// m = w*32..w*32+31 at d = lane as 4 contiguous 16B vector loads.
// Serial FMA chains split into 4 independent accumulators (ILP).
// ---------------------------------------------------------------------------
__global__ __launch_bounds__(256) void ode_chunk(const _Float16* __restrict__ G,
                                                 const float* __restrict__ W1,
                                                 const float* __restrict__ b1,
                                                 float* __restrict__ h_state) {
    const int b = blockIdx.x, t = threadIdx.x;
    const int lane = t & 63, w = t >> 6;
    const int j0 = w * 32 + (lane & 31);       // this thread's z index
    __shared__ float ysw[4][D_SZ];             // per-wave y copies
    __shared__ float part[2][4][D_SZ];         // double-buffered partials

    float w1c[D_SZ];                           // W1[:, j0]
#pragma unroll
    for (int dd = 0; dd < D_SZ; ++dd) w1c[dd] = W1[dd * MLP_SZ + j0];
    const float b1v = b1[j0];

    float hsv = h_state[b * H_SZ + lane];      // all waves (redundant)
    ysw[w][lane] = hsv;
    float k_st[4] = {0.f, 0.f, 0.f, 0.f};

    f16x8 pr[4];
    _Float16 b2pre;
    {
        const _Float16* Gr = G + (size_t)b * GSTR;    // s = 0
        const f16x8* gp = (const f16x8*)(Gr + lane * 128 + w * 32);
#pragma unroll
        for (int v = 0; v < 4; ++v) pr[v] = gp[v];
        b2pre = Gr[8192 + lane];
    }

#pragma unroll 1
    for (int s = 0; s < NC; ++s) {
        float gcur[32];
#pragma unroll
        for (int v = 0; v < 4; ++v)
#pragma unroll
            for (int e = 0; e < 8; ++e) gcur[v * 8 + e] = (float)pr[v][e];
        const float b2cur = (float)b2pre;
        if (s + 1 < NC) {                      // prefetch next step (hidden by stages)
            const _Float16* Gr = G + (size_t)((s + 1) * B_SZ + b) * GSTR;
            const f16x8* gp = (const f16x8*)(Gr + lane * 128 + w * 32);
#pragma unroll
            for (int v = 0; v < 4; ++v) pr[v] = gp[v];
            b2pre = Gr[8192 + lane];
        }

#pragma unroll
        for (int st = 0; st < 4; ++st) {
            float ax = 0.f, ay = 0.f, az = 0.f, aw = 0.f;    // 4 indep chains
#pragma unroll
            for (int dd = 0; dd < D_SZ; dd += 4) {
                const float4 yv = *(const float4*)&ysw[w][dd];
                ax += yv.x * w1c[dd];
                ay += yv.y * w1c[dd + 1];
                az += yv.z * w1c[dd + 2];
                aw += yv.w * w1c[dd + 3];
            }
            const float xx = b1v + ((ax + ay) + (az + aw));
            const float ex = __expf(2.0f * xx);              // tanh(x)=1-2/(e^2x+1)
            const float z = 1.0f - 2.0f / (ex + 1.0f);
            float s0 = 0.f, s1 = 0.f, s2 = 0.f, s3 = 0.f;    // 4 indep chains
#pragma unroll
            for (int q = 0; q < 32; q += 4) {
                s0 += gcur[q]     * rlane(z, q);
                s1 += gcur[q + 1] * rlane(z, q + 1);
                s2 += gcur[q + 2] * rlane(z, q + 2);
                s3 += gcur[q + 3] * rlane(z, q + 3);
            }
            part[st & 1][w][lane] = (s0 + s1) + (s2 + s3);
            __syncthreads();                   // the ONE barrier per stage
            const float kv = b2cur + part[st & 1][0][lane] + part[st & 1][1][lane]
                           + part[st & 1][2][lane] + part[st & 1][3][lane];
            k_st[st] = kv;                     // every wave, identical
            if (st < 3) {
                float y = hsv;
                if (st == 0) y += 0.5f * kv;
                else if (st == 1) y += 0.5f * kv;
                else y += kv;
                ysw[w][lane] = y;              // own copy only
            }
        }
        hsv += (k_st[0] + 2.0f * k_st[1] + 2.0f * k_st[2] + k_st[3]) * (1.0f / 6.0f);
        ysw[w][lane] = hsv;                    // stage-0 y of next step
    }
    if (w == 0) h_state[b * H_SZ + lane] = hsv;
}

// ---------------------------------------------------------------------------
// out = hT @ W_out + b_out             <<<256, 64>>>
// ---------------------------------------------------------------------------
__global__ void out_kernel(const float* __restrict__ h_state, const float* __restrict__ W_out,
                           const float* __restrict__ b_out, float* __restrict__ out) {
    const int b = blockIdx.x, t = threadIdx.x;
    __shared__ float hh[H_SZ];
    hh[t] = h_state[b * H_SZ + t];
    __syncthreads();
    if (t < OUT_SZ) {
        float acc = b_out[t];
        for (int d = 0; d < H_SZ; ++d) acc += hh[d] * W_out[d * OUT_SZ + t];
        out[b * OUT_SZ + t] = acc;
    }
}

extern "C" void kernel_launch(void* const* d_in, const int* in_sizes, int n_in,
                              void* d_out, int out_size, void* d_ws, size_t ws_size,
                              hipStream_t stream) {
    (void)in_sizes; (void)n_in; (void)out_size; (void)ws_size;
    const float* X     = (const float*)d_in[0];
    const float* W_in  = (const float*)d_in[1];
    const float* b_in  = (const float*)d_in[2];
    const float* W1    = (const float*)d_in[3];
    const float* b1    = (const float*)d_in[4];
    const float* W2    = (const float*)d_in[5];
    const float* b2    = (const float*)d_in[6];
    const float* W_out = (const float*)d_in[7];
    const float* b_out = (const float*)d_in[8];
    float* out = (float*)d_out;

    // workspace layout (~205.6 MB total)
    char* ws = (char*)d_ws;
    size_t off = 0;
    auto take = [&](size_t bytes) { void* p = ws + off; off = (off + bytes + 255) & ~(size_t)255; return p; };
    _Float16* Bmat = (_Float16*)take((size_t)NB * KP * 2);      // 35.7 MB
    _Float16* LSc  = (_Float16*)take((size_t)MROWS * KP * 2);   // 34.6 MB
    _Float16* G    = (_Float16*)take((size_t)MROWS * GSTR * 2); // 135.3 MB
    float*    hst  = (float*)take((size_t)B_SZ * H_SZ * 4);     // 64 KB

    build_B<<<NB, 256, 0, stream>>>(W2, b2, Bmat);
    h0_kernel<<<B_SZ, H_SZ, 0, stream>>>(X, W_in, b_in, hst);

    for (int c = 0; c < NCHUNK; ++c) {
        logsig_kernel<<<dim3(B_SZ, NC), 256, 0, stream>>>(X, LSc, c * NC);
        gemm256<<<dim3(1056), 512, 0, stream>>>(
            (const unsigned short*)LSc, (const unsigned short*)Bmat, G);
        ode_chunk<<<B_SZ, 256, 0, stream>>>(G, W1, b1, hst);
    }
    out_kernel<<<B_SZ, H_SZ, 0, stream>>>(hst, W_out, b_out, out);
}

// Round 6
// 1909.914 us; speedup vs baseline: 1.4674x; 1.0341x over previous
//
#include <hip/hip_runtime.h>
#include <hip/hip_bf16.h>
#include <cstdint>
#include <cstddef>

// Problem constants
#define B_SZ   256
#define T_SZ   2049
#define D_SZ   64
#define H_SZ   64
#define MLP_SZ 128
#define NI_SZ  128
#define SEG    16          // (T-1)/NI
#define KDIM   2080        // L = D + D(D-1)/2
#define KP     2112        // padded K = 33*64 (BK=64 tiles)
#define OUT_SZ 10

// GEMM shapes
#define NC     32                  // intervals per chunk
#define NCHUNK (NI_SZ / NC)        // 4
#define MROWS  (NC * B_SZ)         // 8192 rows per chunk GEMM
#define NB     8448                // B rows (8192 G + 64 b2 + pad)
#define GSTR   8256                // stored C cols (8192 G + 64 b2) = G row stride
#define NT     (KP / 64)           // 33 K-tiles

typedef _Float16 f16x8 __attribute__((ext_vector_type(8)));
typedef float    f32x4 __attribute__((ext_vector_type(4)));

__device__ __forceinline__ float rlane(float v, int l) {
    return __uint_as_float(__builtin_amdgcn_readlane(__float_as_uint(v), l));
}

// ---------------------------------------------------------------------------
// Build Bmat (fp16, [NB x KP] row-major), PERMUTED columns-of-G order:
//   row r' = d*128 + m  (d<64, m<128) holds W2[m][d*L + l]
//   rows 8192..8255: b2 row d  |  rows 8256..8447: zeros  |  k pad 2080..2111: 0
// ---------------------------------------------------------------------------
__global__ __launch_bounds__(256) void build_B(const float* __restrict__ W2,
                                               const float* __restrict__ b2,
                                               _Float16* __restrict__ Bm) {
    const int r = blockIdx.x, t = threadIdx.x;
    const float* src = nullptr;
    if (r < 8192) {
        const int d = r >> 7, m = r & 127;
        src = W2 + (size_t)m * (64 * KDIM) + (size_t)d * KDIM;
    } else if (r < 8256) {
        src = b2 + (size_t)(r - 8192) * KDIM;
    }
    _Float16* dst = Bm + (size_t)r * KP;
    for (int l = t; l < KP; l += 256)
        dst[l] = (src && l < KDIM) ? (_Float16)src[l] : (_Float16)0.0f;
}

// ---------------------------------------------------------------------------
// h0 = X[:,0,:] @ W_in + b_in          <<<256, 64>>>
// ---------------------------------------------------------------------------
__global__ void h0_kernel(const float* __restrict__ X, const float* __restrict__ W_in,
                          const float* __restrict__ b_in, float* __restrict__ h_state) {
    const int b = blockIdx.x, t = threadIdx.x;
    __shared__ float x0[D_SZ];
    if (t < D_SZ) x0[t] = X[(size_t)b * T_SZ * D_SZ + t];
    __syncthreads();
    float acc = b_in[t];
    for (int k = 0; k < D_SZ; ++k) acc += x0[k] * W_in[k * H_SZ + t];
    h_state[b * H_SZ + t] = acc;
}

// ---------------------------------------------------------------------------
// Depth-2 log-signature, tile-structured (4x4 register tiles, Lyndon order).
// grid (256, NC), 256 threads. Rows written with stride KP, pad zeroed.
// ---------------------------------------------------------------------------
__global__ __launch_bounds__(256) void logsig_kernel(const float* __restrict__ X,
                                                     _Float16* __restrict__ LS,
                                                     int n0) {
    const int b = blockIdx.x, sl = blockIdx.y, t = threadIdx.x;
    const int n = n0 + sl;
    __shared__ float seg[SEG + 1][D_SZ];
    __shared__ float cum[SEG][D_SZ];
    __shared__ float dlt[SEG][D_SZ];
    __shared__ float Mm[D_SZ][D_SZ + 1];   // +1 pad: transpose reads conflict-free

    const float* Xp = X + ((size_t)b * T_SZ + (size_t)n * SEG) * D_SZ;
    for (int i = t; i < (SEG + 1) * D_SZ / 4; i += 256)
        ((float4*)&seg[0][0])[i] = ((const float4*)Xp)[i];
    __syncthreads();
    for (int i = t; i < SEG * D_SZ; i += 256) {
        const int k = i >> 6, d = i & 63;
        cum[k][d] = seg[k][d] - seg[0][d];
        dlt[k][d] = seg[k + 1][d] - seg[k][d];
    }
    __syncthreads();

    const int ti = t >> 4, tj = t & 15;
    const int i0 = ti * 4, j0 = tj * 4;
    float m4[4][4] = {};
#pragma unroll
    for (int k = 0; k < SEG; ++k) {
        const float4 ci = *(const float4*)&cum[k][i0];
        const float4 dj = *(const float4*)&dlt[k][j0];
        const float* cip = (const float*)&ci;
        const float* djp = (const float*)&dj;
#pragma unroll
        for (int a = 0; a < 4; ++a)
#pragma unroll
            for (int c = 0; c < 4; ++c)
                m4[a][c] += cip[a] * djp[c];
    }
#pragma unroll
    for (int a = 0; a < 4; ++a)
#pragma unroll
        for (int c = 0; c < 4; ++c)
            Mm[i0 + a][j0 + c] = m4[a][c];
    __syncthreads();

    _Float16* out = LS + (size_t)(sl * B_SZ + b) * KP;
    if (t < D_SZ) out[t] = (_Float16)(seg[SEG][t] - seg[0][t]);   // level-1 inc
    if (t < KP - KDIM) out[KDIM + t] = (_Float16)0.0f;            // zero K pad
    if (tj >= ti) {
#pragma unroll
        for (int a = 0; a < 4; ++a) {
            const int i = i0 + a;
#pragma unroll
            for (int c = 0; c < 4; ++c) {
                const int j = j0 + c;
                if (j > i) {
                    const int p = 63 * i - (i * (i - 1)) / 2 + (j - i - 1);
                    out[D_SZ + p] = (_Float16)(0.5f * (m4[a][c] - Mm[j][i]));
                }
            }
        }
    }
}

// ---------------------------------------------------------------------------
// GEMM, 256x256 tile / BK=64 / 8 waves, 16x16x32 MFMA, one-phase register
// pipelining (reads for NEXT cluster issue alongside current MFMA cluster).
//
// KEY FIX vs round 5: the vmcnt asm no longer carries a "memory" clobber.
// LLVM's waitcnt pass treats asm with memory clobber as mayLoad|mayStore on
// all address spaces and inserts s_waitcnt vmcnt(0) lgkmcnt(0) BEFORE it --
// a full drain 2x per K-tile that serialized LDS-read vs MFMA and collapsed
// the distance-2 GLDS prefetch. Bare asm + sched_barrier(0) pin (rule 18;
// m201/HK pattern). Counted-set correctness: no vm ops issue between the
// VMW and its phase walls, so its counted set is position-independent
// within the phase; the leading sched_barrier(0) pins it (prologue: keeps
// it below the 3rd STAGE).
//
// TAIL FIX: main grid = exactly 1024 blocks (N=8192, 4.0 rounds on 256 CUs).
// The 64 b2 columns (cols 8192..8255) are computed by 32 cheap quarter-cost
// blocks (wg 0..31, dispatched first; simple syncthreads-staged 256x64 path)
// -> makespan ~4.1T vs 5T for the 1056-uniform grid.
//
// LDS swizzle / staging / visibility chain: unchanged from round 5 (verified).
// ---------------------------------------------------------------------------
#define GLDS(SRC, DST) __builtin_amdgcn_global_load_lds(                        \
    (__attribute__((address_space(1))) void*)(SRC),                             \
    (__attribute__((address_space(3))) void*)(DST), 16, 0, 0)

#define STAGE(KT, KK, BUF) do {                                                 \
    const unsigned short* _sa = Asrc + (size_t)(KT) * 64 + (KK) * 32;           \
    const unsigned short* _sb = Bsrc + (size_t)(KT) * 64 + (KK) * 32;           \
    unsigned short* _d = ldst + (BUF) * 32768 + (KK) * 8192;                    \
    GLDS(_sa,                  _d);                                             \
    GLDS(_sa + (size_t)128*KP, _d + 4096);                                      \
    GLDS(_sb,                  _d + 16384);                                     \
    GLDS(_sb + (size_t)128*KP, _d + 20480);                                     \
} while (0)

#define BAR() do {                                                              \
    __builtin_amdgcn_sched_barrier(0);                                          \
    __builtin_amdgcn_s_barrier();                                               \
    __builtin_amdgcn_sched_barrier(0);                                          \
} while (0)

// bare counted waitcnt: NO memory clobber (see header comment), pinned by
// a leading sched_barrier(0); trailing wall comes from the following BAR().
#define VMW_(N) do {                                                            \
    __builtin_amdgcn_sched_barrier(0);                                          \
    asm volatile("s_waitcnt vmcnt(" #N ")");                                    \
} while (0)
#define VMW(N) VMW_(N)

// read 4 A-frags (m-blocks MB..MB+3, K-half KK) into frag set S
#define RD_A(S, PTR, KK, MB) do {                                               \
    a##S##0 = *(const f16x8*)((PTR) + (KK) * 8192 + ((MB) + 0) * 512);          \
    a##S##1 = *(const f16x8*)((PTR) + (KK) * 8192 + ((MB) + 1) * 512);          \
    a##S##2 = *(const f16x8*)((PTR) + (KK) * 8192 + ((MB) + 2) * 512);          \
    a##S##3 = *(const f16x8*)((PTR) + (KK) * 8192 + ((MB) + 3) * 512);          \
} while (0)

// read 4 B-frags (K-half KK) into frag set S
#define RD_B(S, PTR, KK) do {                                                   \
    b##S##0 = *(const f16x8*)((PTR) + (KK) * 8192 + 0 * 512);                   \
    b##S##1 = *(const f16x8*)((PTR) + (KK) * 8192 + 1 * 512);                   \
    b##S##2 = *(const f16x8*)((PTR) + (KK) * 8192 + 2 * 512);                   \
    b##S##3 = *(const f16x8*)((PTR) + (KK) * 8192 + 3 * 512);                   \
} while (0)

#define MFMA16(MB, AS, BS) do {                                                 \
    __builtin_amdgcn_s_setprio(1);                                              \
    acc[(MB)+0][0] = __builtin_amdgcn_mfma_f32_16x16x32_f16(a##AS##0, b##BS##0, acc[(MB)+0][0], 0, 0, 0); \
    acc[(MB)+0][1] = __builtin_amdgcn_mfma_f32_16x16x32_f16(a##AS##0, b##BS##1, acc[(MB)+0][1], 0, 0, 0); \
    acc[(MB)+1][0] = __builtin_amdgcn_mfma_f32_16x16x32_f16(a##AS##1, b##BS##0, acc[(MB)+1][0], 0, 0, 0); \
    acc[(MB)+1][1] = __builtin_amdgcn_mfma_f32_16x16x32_f16(a##AS##1, b##BS##1, acc[(MB)+1][1], 0, 0, 0); \
    acc[(MB)+0][2] = __builtin_amdgcn_mfma_f32_16x16x32_f16(a##AS##0, b##BS##2, acc[(MB)+0][2], 0, 0, 0); \
    acc[(MB)+0][3] = __builtin_amdgcn_mfma_f32_16x16x32_f16(a##AS##0, b##BS##3, acc[(MB)+0][3], 0, 0, 0); \
    acc[(MB)+1][2] = __builtin_amdgcn_mfma_f32_16x16x32_f16(a##AS##1, b##BS##2, acc[(MB)+1][2], 0, 0, 0); \
    acc[(MB)+1][3] = __builtin_amdgcn_mfma_f32_16x16x32_f16(a##AS##1, b##BS##3, acc[(MB)+1][3], 0, 0, 0); \
    acc[(MB)+2][0] = __builtin_amdgcn_mfma_f32_16x16x32_f16(a##AS##2, b##BS##0, acc[(MB)+2][0], 0, 0, 0); \
    acc[(MB)+2][1] = __builtin_amdgcn_mfma_f32_16x16x32_f16(a##AS##2, b##BS##1, acc[(MB)+2][1], 0, 0, 0); \
    acc[(MB)+3][0] = __builtin_amdgcn_mfma_f32_16x16x32_f16(a##AS##3, b##BS##0, acc[(MB)+3][0], 0, 0, 0); \
    acc[(MB)+3][1] = __builtin_amdgcn_mfma_f32_16x16x32_f16(a##AS##3, b##BS##1, acc[(MB)+3][1], 0, 0, 0); \
    acc[(MB)+2][2] = __builtin_amdgcn_mfma_f32_16x16x32_f16(a##AS##2, b##BS##2, acc[(MB)+2][2], 0, 0, 0); \
    acc[(MB)+2][3] = __builtin_amdgcn_mfma_f32_16x16x32_f16(a##AS##2, b##BS##3, acc[(MB)+2][3], 0, 0, 0); \
    acc[(MB)+3][2] = __builtin_amdgcn_mfma_f32_16x16x32_f16(a##AS##3, b##BS##2, acc[(MB)+3][2], 0, 0, 0); \
    acc[(MB)+3][3] = __builtin_amdgcn_mfma_f32_16x16x32_f16(a##AS##3, b##BS##3, acc[(MB)+3][3], 0, 0, 0); \
    __builtin_amdgcn_s_setprio(0);                                              \
} while (0)

// One K-tile: 4 clusters, each {reads for NEXT cluster | MFMA current | bar}.
#define TILE_BODY(TT, CUR, DOS1, DOS0, RDN, V1, V2) do {                        \
    const unsigned short* aC = aP + (CUR) * 32768;                              \
    const unsigned short* bC = bP + (CUR) * 32768;                              \
    const unsigned short* aN = aP + ((CUR) ^ 1) * 32768;                        \
    const unsigned short* bN = bP + ((CUR) ^ 1) * 32768;                        \
    /* P0 */                                                                    \
    if (DOS1) { STAGE((TT) + 1, 1, (CUR) ^ 1); }                                \
    RD_A(1, aC, 0, 4);                                                          \
    MFMA16(0, 0, 0);                                                            \
    BAR();                                                                      \
    /* P1 */                                                                    \
    RD_A(0, aC, 1, 0);                                                          \
    RD_B(1, bC, 1);                                                             \
    MFMA16(4, 1, 0);                                                            \
    VMW(V1); BAR();                                                             \
    /* P2 */                                                                    \
    if (DOS0) { STAGE((TT) + 2, 0, (CUR)); }                                    \
    RD_A(1, aC, 1, 4);                                                          \
    MFMA16(0, 0, 1);                                                            \
    BAR();                                                                      \
    /* P3 */                                                                    \
    if (RDN) { RD_A(0, aN, 0, 0); RD_B(0, bN, 0); }                             \
    MFMA16(4, 1, 1);                                                            \
    VMW(V2); BAR();                                                             \
} while (0)

__global__ __launch_bounds__(512, 2) void gemm256(const unsigned short* __restrict__ A,
                                                  const unsigned short* __restrict__ Bm,
                                                  _Float16* __restrict__ C) {
    __shared__ __align__(16) unsigned short lds[65536];    // 128 KiB
    const int t = threadIdx.x;
    const int wg = blockIdx.x;
    const int lane = t & 63, w = t >> 6;
    const int frow = lane & 15, j4 = lane >> 4;

    if (wg < 32) {
        // ---- b2-strip path: C cols 8192..8255, M-tile 256 rows, K=KP ----
        // Simple syncthreads-staged loop (quarter-cost blocks, run first).
        unsigned short* sA = lds;            // [256][32] shorts, 16 KB
        unsigned short* sB = lds + 8192;     // [64][32]  shorts, 4 KB
        const int tileM = wg * 256;
        f32x4 acc[2][4] = {};
        for (int k0 = 0; k0 < KP; k0 += 32) {
            __syncthreads();                 // prev reads done before overwrite
            // stage A (16 wave-instrs): group g=i*8+w, slot g*64+lane
#pragma unroll
            for (int i = 0; i < 2; ++i) {
                const int g = i * 8 + w;
                const int row = g * 16 + (lane >> 2), kc = lane & 3;
                GLDS(A + (size_t)(tileM + row) * KP + k0 + kc * 8,
                     sA + g * 512 + lane * 8);
            }
            // stage B (4 wave-instrs, waves 0..3): rows 8192..8255 of Bm
            if (w < 4) {
                const int row = w * 16 + (lane >> 2), kc = lane & 3;
                GLDS(Bm + (size_t)(8192 + row) * KP + k0 + kc * 8,
                     sB + w * 512 + lane * 8);
            }
            __syncthreads();                 // full drain (implicit) -> visible
            f16x8 bf[4];
#pragma unroll
            for (int ni = 0; ni < 4; ++ni)
                bf[ni] = *(const f16x8*)(sB + (ni * 16 + frow) * 32 + j4 * 8);
#pragma unroll
            for (int mi = 0; mi < 2; ++mi) {
                const f16x8 af = *(const f16x8*)(sA + (w * 32 + mi * 16 + frow) * 32 + j4 * 8);
#pragma unroll
                for (int ni = 0; ni < 4; ++ni)
                    acc[mi][ni] = __builtin_amdgcn_mfma_f32_16x16x32_f16(af, bf[ni],
                                                                         acc[mi][ni], 0, 0, 0);
            }
        }
        const int erow = j4 << 2;
#pragma unroll
        for (int mi = 0; mi < 2; ++mi)
#pragma unroll
            for (int ni = 0; ni < 4; ++ni) {
                const int grow = tileM + w * 32 + mi * 16 + erow;
                const int gcol = 8192 + ni * 16 + frow;
#pragma unroll
                for (int r = 0; r < 4; ++r)
                    C[(size_t)(grow + r) * GSTR + gcol] = (_Float16)acc[mi][ni][r];
            }
        return;
    }

    // ---- main path: 1024 blocks over 32x32 tiles (N=8192 exactly) ----
    // XCD swizzle over 1024 = 8*128: xcd = wg&7 owns bx in [4*xcd, 4*xcd+4).
    const int x  = ((wg - 32) & 7) * 128 + ((wg - 32) >> 3);
    const int bx = x >> 5, by = x & 31;
    const int tileM = bx * 256, tileN = by * 256;

    // staging source (pre-swizzled global address; LDS dest stays linear)
    const int q7s = (t >> 3) & 7;
    const int u   = (t & 7) ^ q7s;
    const int strow = ((t >> 3) << 1) + (u >> 2);   // row within 128-row round
    const int stcol = (u & 3) << 3;                 // element within 32-elem K-half
    const unsigned short* Asrc = A  + (size_t)(tileM + strow) * KP + stcol;
    const unsigned short* Bsrc = Bm + (size_t)(tileN + strow) * KP + stcol;
    unsigned short* ldst = lds + t * 8;

    // fragment read addressing (swizzled)
    const int wm = w >> 2, wn = w & 3;              // 2M x 4N waves
    const int fr2 = frow >> 1;
    const int slot = (((frow & 1) << 2) | j4) ^ fr2;
    const unsigned short* aP = lds + wm * 4096 + fr2 * 64 + slot * 8;
    const unsigned short* bP = lds + 16384 + wn * 2048 + fr2 * 64 + slot * 8;

    f32x4 acc[8][4] = {};
    f16x8 a00, a01, a02, a03, a10, a11, a12, a13;
    f16x8 b00, b01, b02, b03, b10, b11, b12, b13;

    // prologue: S0(0)->Ka(b0), S1(0)->Kb(b0), S0(1)->Ka(b1).
    // VMW(4): S0(0)+S1(0) landed (only S0(1) outstanding); BAR -> visible.
    STAGE(0, 0, 0);
    STAGE(0, 1, 0);
    STAGE(1, 0, 1);
    VMW(4);
    BAR();
    RD_A(0, aP, 0, 0);     // tile0 Ka mb0-3
    RD_B(0, bP, 0);        // tile0 Ka B

    int cur = 0;
#pragma unroll 1
    for (int tt = 0; tt < NT - 2; ++tt) {
        TILE_BODY(tt, cur, 1, 1, 1, 4, 4);    // DOS0=1 always (S0(2..NT-1))
        cur ^= 1;
    }
    TILE_BODY(NT - 2, cur, 1, 0, 1, 4, 0);
    cur ^= 1;
    TILE_BODY(NT - 1, cur, 0, 0, 0, 0, 0);

    // C/D layout: col = lane&15, row = (lane>>4)*4 + reg.
    const int erow = j4 << 2;
#pragma unroll
    for (int mi = 0; mi < 8; ++mi) {
        const int grow = tileM + wm * 128 + mi * 16 + erow;
#pragma unroll
        for (int ni = 0; ni < 4; ++ni) {
            const int gcol = tileN + wn * 64 + ni * 16 + frow;
            _Float16* cp = C + (size_t)grow * GSTR + gcol;
#pragma unroll
            for (int r = 0; r < 4; ++r)
                cp[(size_t)r * GSTR] = (_Float16)acc[mi][ni][r];
        }
    }
}

// ---------------------------------------------------------------------------
// RK4 scan, ONE barrier per stage. One block (4 waves) per batch element.
// G column layout n = d*128 + m (row stride GSTR): thread (w, lane) reads
// m = w*32..w*32+31 at d = lane as 4 contiguous 16B vector loads.
// Serial FMA chains split into 4 independent accumulators (ILP).
// ---------------------------------------------------------------------------
__global__ __launch_bounds__(256) void ode_chunk(const _Float16* __restrict__ G,
                                                 const float* __restrict__ W1,
                                                 const float* __restrict__ b1,
                                                 float* __restrict__ h_state) {
    const int b = blockIdx.x, t = threadIdx.x;
    const int lane = t & 63, w = t >> 6;
    const int j0 = w * 32 + (lane & 31);       // this thread's z index
    __shared__ float ysw[4][D_SZ];             // per-wave y copies
    __shared__ float part[2][4][D_SZ];         // double-buffered partials

    float w1c[D_SZ];                           // W1[:, j0]
#pragma unroll
    for (int dd = 0; dd < D_SZ; ++dd) w1c[dd] = W1[dd * MLP_SZ + j0];
    const float b1v = b1[j0];

    float hsv = h_state[b * H_SZ + lane];      // all waves (redundant)
    ysw[w][lane] = hsv;
    float k_st[4] = {0.f, 0.f, 0.f, 0.f};

    f16x8 pr[4];
    _Float16 b2pre;
    {
        const _Float16* Gr = G + (size_t)b * GSTR;    // s = 0
        const f16x8* gp = (const f16x8*)(Gr + lane * 128 + w * 32);
#pragma unroll
        for (int v = 0; v < 4; ++v) pr[v] = gp[v];
        b2pre = Gr[8192 + lane];
    }

#pragma unroll 1
    for (int s = 0; s < NC; ++s) {
        float gcur[32];
#pragma unroll
        for (int v = 0; v < 4; ++v)
#pragma unroll
            for (int e = 0; e < 8; ++e) gcur[v * 8 + e] = (float)pr[v][e];
        const float b2cur = (float)b2pre;
        if (s + 1 < NC) {                      // prefetch next step (hidden by stages)
            const _Float16* Gr = G + (size_t)((s + 1) * B_SZ + b) * GSTR;
            const f16x8* gp = (const f16x8*)(Gr + lane * 128 + w * 32);
#pragma unroll
            for (int v = 0; v < 4; ++v) pr[v] = gp[v];
            b2pre = Gr[8192 + lane];
        }

#pragma unroll
        for (int st = 0; st < 4; ++st) {
            float ax = 0.f, ay = 0.f, az = 0.f, aw = 0.f;    // 4 indep chains
#pragma unroll
            for (int dd = 0; dd < D_SZ; dd += 4) {
                const float4 yv = *(const float4*)&ysw[w][dd];
                ax += yv.x * w1c[dd];
                ay += yv.y * w1c[dd + 1];
                az += yv.z * w1c[dd + 2];
                aw += yv.w * w1c[dd + 3];
            }
            const float xx = b1v + ((ax + ay) + (az + aw));
            const float ex = __expf(2.0f * xx);              // tanh(x)=1-2/(e^2x+1)
            const float z = 1.0f - 2.0f / (ex + 1.0f);
            float s0 = 0.f, s1 = 0.f, s2 = 0.f, s3 = 0.f;    // 4 indep chains
#pragma unroll
            for (int q = 0; q < 32; q += 4) {
                s0 += gcur[q]     * rlane(z, q);
                s1 += gcur[q + 1] * rlane(z, q + 1);
                s2 += gcur[q + 2] * rlane(z, q + 2);
                s3 += gcur[q + 3] * rlane(z, q + 3);
            }
            part[st & 1][w][lane] = (s0 + s1) + (s2 + s3);
            __syncthreads();                   // the ONE barrier per stage
            const float kv = b2cur + part[st & 1][0][lane] + part[st & 1][1][lane]
                           + part[st & 1][2][lane] + part[st & 1][3][lane];
            k_st[st] = kv;                     // every wave, identical
            if (st < 3) {
                float y = hsv;
                if (st == 0) y += 0.5f * kv;
                else if (st == 1) y += 0.5f * kv;
                else y += kv;
                ysw[w][lane] = y;              // own copy only
            }
        }
        hsv += (k_st[0] + 2.0f * k_st[1] + 2.0f * k_st[2] + k_st[3]) * (1.0f / 6.0f);
        ysw[w][lane] = hsv;                    // stage-0 y of next step
    }
    if (w == 0) h_state[b * H_SZ + lane] = hsv;
}

// ---------------------------------------------------------------------------
// out = hT @ W_out + b_out             <<<256, 64>>>
// ---------------------------------------------------------------------------
__global__ void out_kernel(const float* __restrict__ h_state, const float* __restrict__ W_out,
                           const float* __restrict__ b_out, float* __restrict__ out) {
    const int b = blockIdx.x, t = threadIdx.x;
    __shared__ float hh[H_SZ];
    hh[t] = h_state[b * H_SZ + t];
    __syncthreads();
    if (t < OUT_SZ) {
        float acc = b_out[t];
        for (int d = 0; d < H_SZ; ++d) acc += hh[d] * W_out[d * OUT_SZ + t];
        out[b * OUT_SZ + t] = acc;
    }
}

extern "C" void kernel_launch(void* const* d_in, const int* in_sizes, int n_in,
                              void* d_out, int out_size, void* d_ws, size_t ws_size,
                              hipStream_t stream) {
    (void)in_sizes; (void)n_in; (void)out_size; (void)ws_size;
    const float* X     = (const float*)d_in[0];
    const float* W_in  = (const float*)d_in[1];
    const float* b_in  = (const float*)d_in[2];
    const float* W1    = (const float*)d_in[3];
    const float* b1    = (const float*)d_in[4];
    const float* W2    = (const float*)d_in[5];
    const float* b2    = (const float*)d_in[6];
    const float* W_out = (const float*)d_in[7];
    const float* b_out = (const float*)d_in[8];
    float* out = (float*)d_out;

    // workspace layout (~205.6 MB total)
    char* ws = (char*)d_ws;
    size_t off = 0;
    auto take = [&](size_t bytes) { void* p = ws + off; off = (off + bytes + 255) & ~(size_t)255; return p; };
    _Float16* Bmat = (_Float16*)take((size_t)NB * KP * 2);      // 35.7 MB
    _Float16* LSc  = (_Float16*)take((size_t)MROWS * KP * 2);   // 34.6 MB
    _Float16* G    = (_Float16*)take((size_t)MROWS * GSTR * 2); // 135.3 MB
    float*    hst  = (float*)take((size_t)B_SZ * H_SZ * 4);     // 64 KB

    build_B<<<NB, 256, 0, stream>>>(W2, b2, Bmat);
    h0_kernel<<<B_SZ, H_SZ, 0, stream>>>(X, W_in, b_in, hst);

    for (int c = 0; c < NCHUNK; ++c) {
        logsig_kernel<<<dim3(B_SZ, NC), 256, 0, stream>>>(X, LSc, c * NC);
        gemm256<<<dim3(1056), 512, 0, stream>>>(
            (const unsigned short*)LSc, (const unsigned short*)Bmat, G);
        ode_chunk<<<B_SZ, 256, 0, stream>>>(G, W1, b1, hst);
    }
    out_kernel<<<B_SZ, H_SZ, 0, stream>>>(hst, W_out, b_out, out);
}